// Round 1
// baseline (5269.898 us; speedup 1.0000x reference)
//
#include <hip/hip_runtime.h>
#include <math.h>

#define D_ 1024
#define H_ 16
#define HD_ 64
#define L_ 8
#define V_ 2048
#define FF_ 4096
#define WIN_ 256
#define B_ 2
#define S_ 1024
#define MAXCYC_ 16

typedef __attribute__((ext_vector_type(4))) float f32x4;
typedef __attribute__((ext_vector_type(8))) short s16x8;

__device__ __forceinline__ unsigned short f2bf(float f) {
  union { float f; unsigned int u; } v; v.f = f;
  unsigned int r = v.u + 0x7FFFu + ((v.u >> 16) & 1u);
  return (unsigned short)(r >> 16);
}

__device__ __forceinline__ float wave_sum(float v) {
  #pragma unroll
  for (int m = 1; m < 64; m <<= 1) v += __shfl_xor(v, m, 64);
  return v;
}

// ---------------- conditioning: concat -> proj -> gelu -> layernorm ----------
__global__ __launch_bounds__(256) void cond_kernel(
    const int* mood, const int* raga, const int* taal,
    const float* tempo, const float* duration,
    const float* mood_emb, const float* raga_emb, const float* taal_emb,
    const float* tempo_w, const float* tempo_b, const float* dur_w, const float* dur_b,
    const float* proj_w, const float* proj_b, const float* ln_g, const float* ln_b,
    float* cond)
{
  int b = blockIdx.x;
  int t = threadIdx.x;
  __shared__ float feat[192];
  __shared__ float red[4];
  if (t < 64)        feat[t] = mood_emb[mood[b]*64 + t];
  else if (t < 128)  feat[t] = raga_emb[raga[b]*64 + (t-64)];
  else if (t < 160)  feat[t] = taal_emb[taal[b]*32 + (t-128)];
  else if (t < 176)  feat[t] = tempo[b]*tempo_w[t-160] + tempo_b[t-160];
  else if (t < 192)  feat[t] = duration[b]*dur_w[t-176] + dur_b[t-176];
  __syncthreads();
  float g[4];
  #pragma unroll
  for (int r = 0; r < 4; ++r) {
    int j = t + 256*r;
    const float* w = proj_w + (size_t)j*192;
    float acc = proj_b[j];
    for (int f = 0; f < 192; ++f) acc += feat[f]*w[f];
    g[r] = 0.5f * acc * (1.0f + erff(acc * 0.7071067811865475f));
  }
  int lane = t & 63, wv = t >> 6;
  float s1 = g[0]+g[1]+g[2]+g[3];
  s1 = wave_sum(s1);
  if (lane == 0) red[wv] = s1;
  __syncthreads();
  float mu = (red[0]+red[1]+red[2]+red[3]) * (1.0f/1024.0f);
  __syncthreads();
  float vs = 0.f;
  #pragma unroll
  for (int r = 0; r < 4; ++r) { float d = g[r]-mu; vs += d*d; }
  vs = wave_sum(vs);
  if (lane == 0) red[wv] = vs;
  __syncthreads();
  float var = (red[0]+red[1]+red[2]+red[3]) * (1.0f/1024.0f);
  float is = rsqrtf(var + 1e-5f);
  #pragma unroll
  for (int r = 0; r < 4; ++r) {
    int j = t + 256*r;
    cond[(size_t)b*D_ + j] = (g[r]-mu)*is*ln_g[j] + ln_b[j];
  }
}

// ---------------- embedding sum -------------------------------------------
__global__ __launch_bounds__(256) void embed_kernel(
    const int* tokens, const float* tok_emb, const float* cond,
    const float* cycle_emb, const float* strength_emb, const int* tcl_p, float* x)
{
  int row = blockIdx.x;          // b*S + s
  int b = row >> 10, s = row & 1023;
  int tcl = tcl_p[0];
  int cyc = tcl < MAXCYC_ ? tcl : MAXCYC_;
  int pr  = s % cyc;
  int str = (s % tcl == 0) ? 0 : 3;
  int tok = tokens[row];
  int d = threadIdx.x * 4;
  float4 a = *(const float4*)&tok_emb[(size_t)tok*D_ + d];
  float4 c = *(const float4*)&cond[(size_t)b*D_ + d];
  float4 p = *(const float4*)&cycle_emb[(size_t)pr*D_ + d];
  float4 e = *(const float4*)&strength_emb[(size_t)str*D_ + d];
  float4 o; o.x=a.x+c.x+p.x+e.x; o.y=a.y+c.y+p.y+e.y; o.z=a.z+c.z+p.z+e.z; o.w=a.w+c.w+p.w+e.w;
  *(float4*)&x[(size_t)row*D_ + d] = o;
}

// ---------------- rmsnorm -> bf16 ------------------------------------------
__global__ __launch_bounds__(256) void rmsnorm_kernel(
    const float* x, const float* w, unsigned short* out)
{
  int row = blockIdx.x;
  int t = threadIdx.x;
  __shared__ float red[4];
  const float* xr = x + (size_t)row*D_;
  float4 v = *(const float4*)&xr[t*4];
  float ss = v.x*v.x + v.y*v.y + v.z*v.z + v.w*v.w;
  ss = wave_sum(ss);
  int lane = t & 63, wv = t >> 6;
  if (lane == 0) red[wv] = ss;
  __syncthreads();
  float total = red[0]+red[1]+red[2]+red[3];
  float scale = rsqrtf(total * (1.0f/1024.0f) + 1e-5f);
  float4 wv4 = *(const float4*)&w[t*4];
  ushort4 o;
  o.x = f2bf(wv4.x * v.x * scale);
  o.y = f2bf(wv4.y * v.y * scale);
  o.z = f2bf(wv4.z * v.z * scale);
  o.w = f2bf(wv4.w * v.w * scale);
  *(ushort4*)&out[(size_t)row*D_ + t*4] = o;
}

// ---------------- rope tables + apply ---------------------------------------
__global__ __launch_bounds__(256) void rope_table_kernel(float* costab, float* sintab)
{
  int i = blockIdx.x*256 + threadIdx.x;   // s*64 + d
  int s = i >> 6, d = i & 63;
  float inv = powf(10000.0f, -(float)(d & 31) * (1.0f/32.0f));
  float ang = (float)s * inv;
  float sn, cs;
  sincosf(ang, &sn, &cs);
  costab[i] = cs; sintab[i] = sn;
}

__global__ __launch_bounds__(256) void rope_kernel(
    float* q, float* k, const float* costab, const float* sintab)
{
  int p = blockIdx.x*256 + threadIdx.x;   // pair index
  float* ten = blockIdx.y ? k : q;
  int row = p >> 9;                        // b*S + s  (512 pairs per 1024-row)
  int i = p & 511;
  int s = row & 1023;
  int j = i & 31;
  int d0 = (i >> 5)*64 + 2*j;
  size_t base = (size_t)row*D_ + d0;
  float2 v   = *(float2*)&ten[base];
  float2 cs2 = *(const float2*)&costab[s*64 + 2*j];
  float2 sn2 = *(const float2*)&sintab[s*64 + 2*j];
  float o0 = v.x*cs2.x - v.y*sn2.x;   // even: x*cos - x_odd*sin
  float o1 = v.y*cs2.y + v.x*sn2.y;   // odd:  x*cos + x_even*sin
  float2 o; o.x = o0; o.y = o1;
  *(float2*)&ten[base] = o;
}

// ---------------- sliding-window flash attention ----------------------------
__global__ __launch_bounds__(128) void attn_kernel(
    const float* q, const float* k, const float* v, unsigned short* y)
{
  __shared__ float Ks[64*64];
  __shared__ float Vs[64*64];
  int qb = blockIdx.x;     // S/128
  int h  = blockIdx.y;
  int b  = blockIdx.z;
  int t  = threadIdx.x;    // 0..127, one query each
  int s  = qb*128 + t;

  const float* qrow = q + ((size_t)(b*S_ + s)*D_ + h*HD_);
  float qr[64];
  #pragma unroll
  for (int i = 0; i < 16; ++i) {
    float4 tmp = *(const float4*)&qrow[i*4];
    qr[i*4+0]=tmp.x; qr[i*4+1]=tmp.y; qr[i*4+2]=tmp.z; qr[i*4+3]=tmp.w;
  }
  float acc[64];
  #pragma unroll
  for (int i = 0; i < 64; ++i) acc[i] = 0.f;
  float m = -1e30f, l = 0.f;

  int lo = qb*128 - (WIN_-1); if (lo < 0) lo = 0;
  int kt0 = lo & ~63;
  int kend = qb*128 + 127;
  int r0 = t >> 4;
  int c  = (t & 15)*4;
  for (int kt = kt0; kt <= kend; kt += 64) {
    __syncthreads();
    #pragma unroll
    for (int p = 0; p < 8; ++p) {
      int r = p*8 + r0;
      size_t src = (size_t)(b*S_ + kt + r)*D_ + h*HD_ + c;
      *(float4*)&Ks[r*64 + c] = *(const float4*)&k[src];
      *(float4*)&Vs[r*64 + c] = *(const float4*)&v[src];
    }
    __syncthreads();
    int jmax = s - kt;             if (jmax > 63) jmax = 63;
    int jmin = (s - (WIN_-1)) - kt; if (jmin < 0) jmin = 0;
    for (int j = jmin; j <= jmax; ++j) {
      float dot = 0.f;
      #pragma unroll
      for (int i = 0; i < 16; ++i) {
        float4 kv = *(const float4*)&Ks[j*64 + i*4];
        dot += qr[i*4]*kv.x + qr[i*4+1]*kv.y + qr[i*4+2]*kv.z + qr[i*4+3]*kv.w;
      }
      float sc = dot * 0.125f;
      if (sc > m) {
        float f = __expf(m - sc);
        #pragma unroll
        for (int i = 0; i < 64; ++i) acc[i] *= f;
        l *= f; m = sc;
      }
      float p = __expf(sc - m);
      l += p;
      #pragma unroll
      for (int i = 0; i < 16; ++i) {
        float4 vv = *(const float4*)&Vs[j*64 + i*4];
        acc[i*4]   += p*vv.x; acc[i*4+1] += p*vv.y;
        acc[i*4+2] += p*vv.z; acc[i*4+3] += p*vv.w;
      }
    }
  }
  float inv = 1.0f / l;
  unsigned short* yr = y + ((size_t)(b*S_ + s)*D_ + h*HD_);
  #pragma unroll
  for (int i = 0; i < 16; ++i) {
    ushort4 o;
    o.x = f2bf(acc[i*4+0]*inv); o.y = f2bf(acc[i*4+1]*inv);
    o.z = f2bf(acc[i*4+2]*inv); o.w = f2bf(acc[i*4+3]*inv);
    *(ushort4*)&yr[i*4] = o;
  }
}

// ---------------- MFMA GEMM:  C[M,N] (+)= A[M,K](bf16) * W[N,K](f32)^T -------
// tile 128x128, BK=32, 256 threads (4 waves 2x2), 16x16x32 bf16 MFMA.
// EPI: 0 = store f32, 1 = add into f32, 2 = silu(U)*acc -> bf16
template<int EPI>
__device__ __forceinline__ void gemm_core(
    const unsigned short* __restrict__ A, const float* __restrict__ W,
    float* __restrict__ Cf, unsigned short* __restrict__ Cb,
    const float* __restrict__ U,
    int K, int lda, int ldw, int ldc)
{
  __shared__ unsigned short As[128*32];
  __shared__ unsigned short Ws[128*32];
  int tid = threadIdx.x;
  int lane = tid & 63, wave = tid >> 6;
  int wr = (wave >> 1)*64, wc = (wave & 1)*64;
  size_t bm = (size_t)blockIdx.x * 128, bn = (size_t)blockIdx.y * 128;

  f32x4 acc[4][4];
  #pragma unroll
  for (int i = 0; i < 4; ++i)
    #pragma unroll
    for (int j = 0; j < 4; ++j)
      acc[i][j] = (f32x4){0.f, 0.f, 0.f, 0.f};

  int sr = tid >> 3;        // 0..31
  int sc = (tid & 7) * 4;   // 0..28
  int fr = lane & 15, fk = (lane >> 4)*8;

  for (int kt = 0; kt < K; kt += 32) {
    #pragma unroll
    for (int p = 0; p < 4; ++p) {
      int r = p*32 + sr;
      ushort4 av = *(const ushort4*)(A + (bm + r)*(size_t)lda + kt + sc);
      *(ushort4*)&As[r*32 + sc] = av;
      float4 wv = *(const float4*)(W + (bn + r)*(size_t)ldw + kt + sc);
      ushort4 wb;
      wb.x = f2bf(wv.x); wb.y = f2bf(wv.y); wb.z = f2bf(wv.z); wb.w = f2bf(wv.w);
      *(ushort4*)&Ws[r*32 + sc] = wb;
    }
    __syncthreads();
    s16x8 af[4], bfv[4];
    #pragma unroll
    for (int i = 0; i < 4; ++i) {
      af[i]  = *(const s16x8*)&As[(wr + i*16 + fr)*32 + fk];
      bfv[i] = *(const s16x8*)&Ws[(wc + i*16 + fr)*32 + fk];
    }
    #pragma unroll
    for (int i = 0; i < 4; ++i)
      #pragma unroll
      for (int j = 0; j < 4; ++j)
        acc[i][j] = __builtin_amdgcn_mfma_f32_16x16x32_bf16(af[i], bfv[j], acc[i][j], 0, 0, 0);
    __syncthreads();
  }

  int fq = (lane >> 4)*4;
  #pragma unroll
  for (int i = 0; i < 4; ++i) {
    #pragma unroll
    for (int j = 0; j < 4; ++j) {
      size_t row = bm + wr + i*16 + fq;
      size_t col = bn + wc + j*16 + fr;
      #pragma unroll
      for (int qi = 0; qi < 4; ++qi) {
        float val = acc[i][j][qi];
        size_t idx = (row + qi)*(size_t)ldc + col;
        if (EPI == 0) {
          Cf[idx] = val;
        } else if (EPI == 1) {
          Cf[idx] += val;
        } else {
          float uu = U[idx];
          float su = uu / (1.0f + __expf(-uu));
          Cb[idx] = f2bf(su * val);
        }
      }
    }
  }
}

template<int EPI>
__global__ __launch_bounds__(256) void gemm_nt(
    const unsigned short* __restrict__ A, const float* __restrict__ W,
    float* __restrict__ Cf, unsigned short* __restrict__ Cb,
    const float* __restrict__ U, int K, int lda, int ldw, int ldc)
{
  gemm_core<EPI>(A, W, Cf, Cb, U, K, lda, ldw, ldc);
}

__global__ __launch_bounds__(256) void gemm_qkv(
    const unsigned short* __restrict__ A,
    const float* __restrict__ Wq, const float* __restrict__ Wk, const float* __restrict__ Wv,
    float* __restrict__ Cq, float* __restrict__ Ck, float* __restrict__ Cv,
    int K, int lda, int ldw, int ldc)
{
  const float* W = (blockIdx.z == 0) ? Wq : ((blockIdx.z == 1) ? Wk : Wv);
  float* C       = (blockIdx.z == 0) ? Cq : ((blockIdx.z == 1) ? Ck : Cv);
  gemm_core<0>(A, W, C, nullptr, nullptr, K, lda, ldw, ldc);
}

// ---------------- host launcher ---------------------------------------------
extern "C" void kernel_launch(void* const* d_in, const int* in_sizes, int n_in,
                              void* d_out, int out_size, void* d_ws, size_t ws_size,
                              hipStream_t stream)
{
  const int*   tokens    = (const int*)d_in[0];
  const int*   mood      = (const int*)d_in[1];
  const int*   raga      = (const int*)d_in[2];
  const int*   taal      = (const int*)d_in[3];
  const float* tempo     = (const float*)d_in[4];
  const float* duration  = (const float*)d_in[5];
  const int*   tcl       = (const int*)d_in[6];
  const float* tok_emb   = (const float*)d_in[7];
  const float* mood_emb  = (const float*)d_in[8];
  const float* raga_emb  = (const float*)d_in[9];
  const float* taal_emb  = (const float*)d_in[10];
  const float* tempo_w   = (const float*)d_in[11];
  const float* tempo_b   = (const float*)d_in[12];
  const float* dur_w     = (const float*)d_in[13];
  const float* dur_b     = (const float*)d_in[14];
  const float* proj_w    = (const float*)d_in[15];
  const float* proj_b    = (const float*)d_in[16];
  const float* ln_g      = (const float*)d_in[17];
  const float* ln_b      = (const float*)d_in[18];
  const float* cycle_emb = (const float*)d_in[19];
  const float* strength_e= (const float*)d_in[20];
  const float* l_anorm   = (const float*)d_in[21];
  const float* l_fnorm   = (const float*)d_in[22];
  const float* l_q       = (const float*)d_in[23];
  const float* l_k       = (const float*)d_in[24];
  const float* l_v       = (const float*)d_in[25];
  const float* l_o       = (const float*)d_in[26];
  const float* l_w1      = (const float*)d_in[27];
  const float* l_w2      = (const float*)d_in[28];
  const float* l_w3      = (const float*)d_in[29];
  const float* final_norm= (const float*)d_in[30];
  const float* head_w    = (const float*)d_in[31];

  size_t off = 0;
  char* wsb = (char*)d_ws;
  auto alloc = [&](size_t bytes) -> char* {
    char* p = wsb + off;
    off += (bytes + 255) & ~(size_t)255;
    return p;
  };
  float*          condb  = (float*)alloc((size_t)B_*D_*4);
  float*          costab = (float*)alloc((size_t)S_*HD_*4);
  float*          sintab = (float*)alloc((size_t)S_*HD_*4);
  float*          x      = (float*)alloc((size_t)B_*S_*D_*4);
  unsigned short* hbuf   = (unsigned short*)alloc((size_t)B_*S_*D_*2);
  float*          qb     = (float*)alloc((size_t)B_*S_*D_*4);
  float*          kb     = (float*)alloc((size_t)B_*S_*D_*4);
  float*          vb     = (float*)alloc((size_t)B_*S_*D_*4);
  unsigned short* yb     = (unsigned short*)alloc((size_t)B_*S_*D_*2);
  float*          ub     = (float*)alloc((size_t)B_*S_*FF_*4);
  unsigned short* tb     = (unsigned short*)alloc((size_t)B_*S_*FF_*2);

  rope_table_kernel<<<(S_*HD_)/256, 256, 0, stream>>>(costab, sintab);
  cond_kernel<<<B_, 256, 0, stream>>>(mood, raga, taal, tempo, duration,
      mood_emb, raga_emb, taal_emb, tempo_w, tempo_b, dur_w, dur_b,
      proj_w, proj_b, ln_g, ln_b, condb);
  embed_kernel<<<B_*S_, 256, 0, stream>>>(tokens, tok_emb, condb, cycle_emb,
      strength_e, tcl, x);

  const int rows = B_*S_;   // 2048
  for (int l = 0; l < L_; ++l) {
    size_t dd = (size_t)l*D_*D_;
    size_t fd = (size_t)l*FF_*D_;
    rmsnorm_kernel<<<rows, 256, 0, stream>>>(x, l_anorm + (size_t)l*D_, hbuf);
    gemm_qkv<<<dim3(rows/128, D_/128, 3), 256, 0, stream>>>(
        hbuf, l_q + dd, l_k + dd, l_v + dd, qb, kb, vb, D_, D_, D_, D_);
    rope_kernel<<<dim3((rows*512)/256, 2), 256, 0, stream>>>(qb, kb, costab, sintab);
    attn_kernel<<<dim3(S_/128, H_, B_), 128, 0, stream>>>(qb, kb, vb, yb);
    gemm_nt<1><<<dim3(rows/128, D_/128), 256, 0, stream>>>(
        yb, l_o + dd, x, nullptr, nullptr, D_, D_, D_, D_);
    rmsnorm_kernel<<<rows, 256, 0, stream>>>(x, l_fnorm + (size_t)l*D_, hbuf);
    gemm_nt<0><<<dim3(rows/128, FF_/128), 256, 0, stream>>>(
        hbuf, l_w1 + fd, ub, nullptr, nullptr, D_, D_, D_, FF_);
    gemm_nt<2><<<dim3(rows/128, FF_/128), 256, 0, stream>>>(
        hbuf, l_w3 + fd, nullptr, tb, ub, D_, D_, D_, FF_);
    gemm_nt<1><<<dim3(rows/128, D_/128), 256, 0, stream>>>(
        tb, l_w2 + (size_t)l*D_*FF_, x, nullptr, nullptr, FF_, FF_, FF_, D_);
  }
  rmsnorm_kernel<<<rows, 256, 0, stream>>>(x, final_norm, hbuf);
  gemm_nt<0><<<dim3(rows/128, V_/128), 256, 0, stream>>>(
      hbuf, head_w, (float*)d_out, nullptr, nullptr, D_, D_, D_, V_);
}

// Round 2
// 3276.194 us; speedup vs baseline: 1.6085x; 1.6085x over previous
//
#include <hip/hip_runtime.h>
#include <math.h>

#define D_ 1024
#define H_ 16
#define HD_ 64
#define L_ 8
#define V_ 2048
#define FF_ 4096
#define WIN_ 256
#define B_ 2
#define S_ 1024
#define MAXCYC_ 16

typedef __attribute__((ext_vector_type(4))) float f32x4;
typedef __attribute__((ext_vector_type(8))) short s16x8;

__device__ __forceinline__ unsigned short f2bf(float f) {
  union { float f; unsigned int u; } v; v.f = f;
  unsigned int r = v.u + 0x7FFFu + ((v.u >> 16) & 1u);
  return (unsigned short)(r >> 16);
}

__device__ __forceinline__ float wave_sum(float v) {
  #pragma unroll
  for (int m = 1; m < 64; m <<= 1) v += __shfl_xor(v, m, 64);
  return v;
}

// ---------------- f32 -> bf16 convert (weights) ------------------------------
__global__ __launch_bounds__(256) void cvt_kernel(
    const float* __restrict__ src, unsigned short* __restrict__ dst, int n8)
{
  int i = blockIdx.x*256 + threadIdx.x;
  if (i >= n8) return;
  const float4* s = (const float4*)src + (size_t)i*2;
  float4 a = s[0], b = s[1];
  ushort4 lo, hi;
  lo.x = f2bf(a.x); lo.y = f2bf(a.y); lo.z = f2bf(a.z); lo.w = f2bf(a.w);
  hi.x = f2bf(b.x); hi.y = f2bf(b.y); hi.z = f2bf(b.z); hi.w = f2bf(b.w);
  *(ushort4*)(dst + (size_t)i*8)     = lo;
  *(ushort4*)(dst + (size_t)i*8 + 4) = hi;
}

// ---------------- conditioning ----------------------------------------------
__global__ __launch_bounds__(256) void cond_kernel(
    const int* mood, const int* raga, const int* taal,
    const float* tempo, const float* duration,
    const float* mood_emb, const float* raga_emb, const float* taal_emb,
    const float* tempo_w, const float* tempo_b, const float* dur_w, const float* dur_b,
    const float* proj_w, const float* proj_b, const float* ln_g, const float* ln_b,
    float* cond)
{
  int b = blockIdx.x;
  int t = threadIdx.x;
  __shared__ float feat[192];
  __shared__ float red[4];
  if (t < 64)        feat[t] = mood_emb[mood[b]*64 + t];
  else if (t < 128)  feat[t] = raga_emb[raga[b]*64 + (t-64)];
  else if (t < 160)  feat[t] = taal_emb[taal[b]*32 + (t-128)];
  else if (t < 176)  feat[t] = tempo[b]*tempo_w[t-160] + tempo_b[t-160];
  else if (t < 192)  feat[t] = duration[b]*dur_w[t-176] + dur_b[t-176];
  __syncthreads();
  float g[4];
  #pragma unroll
  for (int r = 0; r < 4; ++r) {
    int j = t + 256*r;
    const float* w = proj_w + (size_t)j*192;
    float acc = proj_b[j];
    for (int f = 0; f < 192; ++f) acc += feat[f]*w[f];
    g[r] = 0.5f * acc * (1.0f + erff(acc * 0.7071067811865475f));
  }
  int lane = t & 63, wv = t >> 6;
  float s1 = g[0]+g[1]+g[2]+g[3];
  s1 = wave_sum(s1);
  if (lane == 0) red[wv] = s1;
  __syncthreads();
  float mu = (red[0]+red[1]+red[2]+red[3]) * (1.0f/1024.0f);
  __syncthreads();
  float vs = 0.f;
  #pragma unroll
  for (int r = 0; r < 4; ++r) { float d = g[r]-mu; vs += d*d; }
  vs = wave_sum(vs);
  if (lane == 0) red[wv] = vs;
  __syncthreads();
  float var = (red[0]+red[1]+red[2]+red[3]) * (1.0f/1024.0f);
  float is = rsqrtf(var + 1e-5f);
  #pragma unroll
  for (int r = 0; r < 4; ++r) {
    int j = t + 256*r;
    cond[(size_t)b*D_ + j] = (g[r]-mu)*is*ln_g[j] + ln_b[j];
  }
}

// ---------------- embedding sum ----------------------------------------------
__global__ __launch_bounds__(256) void embed_kernel(
    const int* tokens, const float* tok_emb, const float* cond,
    const float* cycle_emb, const float* strength_emb, const int* tcl_p, float* x)
{
  int row = blockIdx.x;
  int b = row >> 10, s = row & 1023;
  int tcl = tcl_p[0];
  int cyc = tcl < MAXCYC_ ? tcl : MAXCYC_;
  int pr  = s % cyc;
  int str = (s % tcl == 0) ? 0 : 3;
  int tok = tokens[row];
  int d = threadIdx.x * 4;
  float4 a = *(const float4*)&tok_emb[(size_t)tok*D_ + d];
  float4 c = *(const float4*)&cond[(size_t)b*D_ + d];
  float4 p = *(const float4*)&cycle_emb[(size_t)pr*D_ + d];
  float4 e = *(const float4*)&strength_emb[(size_t)str*D_ + d];
  float4 o; o.x=a.x+c.x+p.x+e.x; o.y=a.y+c.y+p.y+e.y; o.z=a.z+c.z+p.z+e.z; o.w=a.w+c.w+p.w+e.w;
  *(float4*)&x[(size_t)row*D_ + d] = o;
}

// ---------------- rmsnorm -> bf16 --------------------------------------------
__global__ __launch_bounds__(256) void rmsnorm_kernel(
    const float* x, const float* w, unsigned short* out)
{
  int row = blockIdx.x;
  int t = threadIdx.x;
  __shared__ float red[4];
  const float* xr = x + (size_t)row*D_;
  float4 v = *(const float4*)&xr[t*4];
  float ss = v.x*v.x + v.y*v.y + v.z*v.z + v.w*v.w;
  ss = wave_sum(ss);
  int lane = t & 63, wv = t >> 6;
  if (lane == 0) red[wv] = ss;
  __syncthreads();
  float total = red[0]+red[1]+red[2]+red[3];
  float scale = rsqrtf(total * (1.0f/1024.0f) + 1e-5f);
  float4 wv4 = *(const float4*)&w[t*4];
  ushort4 o;
  o.x = f2bf(wv4.x * v.x * scale);
  o.y = f2bf(wv4.y * v.y * scale);
  o.z = f2bf(wv4.z * v.z * scale);
  o.w = f2bf(wv4.w * v.w * scale);
  *(ushort4*)&out[(size_t)row*D_ + t*4] = o;
}

// ---------------- rope tables + apply -----------------------------------------
__global__ __launch_bounds__(256) void rope_table_kernel(float* costab, float* sintab)
{
  int i = blockIdx.x*256 + threadIdx.x;
  int s = i >> 6, d = i & 63;
  float inv = powf(10000.0f, -(float)(d & 31) * (1.0f/32.0f));
  float ang = (float)s * inv;
  float sn, cs;
  sincosf(ang, &sn, &cs);
  costab[i] = cs; sintab[i] = sn;
}

__global__ __launch_bounds__(256) void rope_kernel(
    float* q, float* k, const float* costab, const float* sintab)
{
  int p = blockIdx.x*256 + threadIdx.x;
  float* ten = blockIdx.y ? k : q;
  int row = p >> 9;
  int i = p & 511;
  int s = row & 1023;
  int j = i & 31;
  int d0 = (i >> 5)*64 + 2*j;
  size_t base = (size_t)row*D_ + d0;
  float2 v   = *(float2*)&ten[base];
  float2 cs2 = *(const float2*)&costab[s*64 + 2*j];
  float2 sn2 = *(const float2*)&sintab[s*64 + 2*j];
  float o0 = v.x*cs2.x - v.y*sn2.x;
  float o1 = v.y*cs2.y + v.x*sn2.y;
  float2 o; o.x = o0; o.y = o1;
  *(float2*)&ten[base] = o;
}

// ---------------- sliding-window flash attention (4 threads / query) ----------
#define KPAD_ 68
__global__ __launch_bounds__(256) void attn_kernel(
    const float* __restrict__ q, const float* __restrict__ k,
    const float* __restrict__ v, unsigned short* __restrict__ y)
{
  __shared__ float Ks[64*KPAD_];
  __shared__ float Vs[64*KPAD_];
  int qb0 = blockIdx.x * 64;
  int h  = blockIdx.y;
  int b  = blockIdx.z;
  int t  = threadIdx.x;        // 256 threads
  int ql = t >> 2;             // query within block: 0..63
  int dp = (t & 3) * 16;       // 16-dim slice
  int s  = qb0 + ql;

  const float* qrow = q + ((size_t)(b*S_ + s)*D_ + h*HD_ + dp);
  float qr[16];
  #pragma unroll
  for (int i = 0; i < 4; ++i) {
    float4 tmp = *(const float4*)&qrow[i*4];
    qr[i*4+0]=tmp.x; qr[i*4+1]=tmp.y; qr[i*4+2]=tmp.z; qr[i*4+3]=tmp.w;
  }
  float acc[16];
  #pragma unroll
  for (int i = 0; i < 16; ++i) acc[i] = 0.f;
  float m = -1e30f, l = 0.f;

  int lo = qb0 - (WIN_-1); if (lo < 0) lo = 0;
  int kt0 = lo & ~63;
  int sr = t >> 2;             // staging row 0..63
  int sc = (t & 3) * 16;       // staging col

  for (int kt = kt0; kt <= qb0 + 63; kt += 64) {
    __syncthreads();
    size_t srcb = (size_t)(b*S_ + kt + sr)*D_ + h*HD_ + sc;
    #pragma unroll
    for (int i = 0; i < 4; ++i) {
      *(float4*)&Ks[sr*KPAD_ + sc + i*4] = *(const float4*)&k[srcb + i*4];
      *(float4*)&Vs[sr*KPAD_ + sc + i*4] = *(const float4*)&v[srcb + i*4];
    }
    __syncthreads();
    int jmax = s - kt;              if (jmax > 63) jmax = 63;
    int jmin = (s - (WIN_-1)) - kt; if (jmin < 0) jmin = 0;
    for (int j = jmin; j <= jmax; ++j) {
      const float* kr = &Ks[j*KPAD_ + dp];
      float dot = 0.f;
      #pragma unroll
      for (int i = 0; i < 4; ++i) {
        float4 kv = *(const float4*)&kr[i*4];
        dot += qr[i*4]*kv.x + qr[i*4+1]*kv.y + qr[i*4+2]*kv.z + qr[i*4+3]*kv.w;
      }
      dot += __shfl_xor(dot, 1, 64);
      dot += __shfl_xor(dot, 2, 64);
      float sc2 = dot * 0.125f;
      if (sc2 > m) {
        float f = __expf(m - sc2);
        #pragma unroll
        for (int i = 0; i < 16; ++i) acc[i] *= f;
        l *= f; m = sc2;
      }
      float p = __expf(sc2 - m);
      l += p;
      const float* vr = &Vs[j*KPAD_ + dp];
      #pragma unroll
      for (int i = 0; i < 4; ++i) {
        float4 vv = *(const float4*)&vr[i*4];
        acc[i*4+0] += p*vv.x; acc[i*4+1] += p*vv.y;
        acc[i*4+2] += p*vv.z; acc[i*4+3] += p*vv.w;
      }
    }
  }
  float inv = 1.0f / l;
  unsigned short* yr = y + ((size_t)(b*S_ + s)*D_ + h*HD_ + dp);
  #pragma unroll
  for (int i = 0; i < 4; ++i) {
    ushort4 o;
    o.x = f2bf(acc[i*4+0]*inv); o.y = f2bf(acc[i*4+1]*inv);
    o.z = f2bf(acc[i*4+2]*inv); o.w = f2bf(acc[i*4+3]*inv);
    *(ushort4*)&yr[i*4] = o;
  }
}

// ---------------- MFMA GEMM, bf16 weights (fast path) -------------------------
// C[M,N] (+)= A[M,K](bf16) * W[N,K](bf16)^T.  128x128 tile, BK=32, 4 waves 2x2.
// EPI: 0 = store f32, 1 = add into f32, 2 = silu(U)*acc -> bf16
__device__ __forceinline__ int swz(int r, int c) {
  return r*32 + (c ^ ((r & 3) << 3));
}

template<int EPI>
__device__ __forceinline__ void gemm_core_b(
    const unsigned short* __restrict__ A, const unsigned short* __restrict__ W,
    float* __restrict__ Cf, unsigned short* __restrict__ Cb,
    const float* __restrict__ U,
    int K, int lda, int ldw, int ldc)
{
  __shared__ unsigned short As[128*32];
  __shared__ unsigned short Ws[128*32];
  int tid = threadIdx.x;
  int lane = tid & 63, wave = tid >> 6;
  int wr = (wave >> 1)*64, wc = (wave & 1)*64;
  size_t bm = (size_t)blockIdx.x * 128, bn = (size_t)blockIdx.y * 128;

  f32x4 acc[4][4];
  #pragma unroll
  for (int i = 0; i < 4; ++i)
    #pragma unroll
    for (int j = 0; j < 4; ++j)
      acc[i][j] = (f32x4){0.f, 0.f, 0.f, 0.f};

  int sr = tid >> 2;        // 0..63
  int sc = (tid & 3) * 8;   // elem col 0,8,16,24
  int fr = lane & 15, fk = (lane >> 4)*8;

  for (int kt = 0; kt < K; kt += 32) {
    #pragma unroll
    for (int p = 0; p < 2; ++p) {
      int r = p*64 + sr;
      s16x8 av = *(const s16x8*)(A + (bm + r)*(size_t)lda + kt + sc);
      *(s16x8*)&As[swz(r, sc)] = av;
      s16x8 wv = *(const s16x8*)(W + (bn + r)*(size_t)ldw + kt + sc);
      *(s16x8*)&Ws[swz(r, sc)] = wv;
    }
    __syncthreads();
    s16x8 af[4], bfv[4];
    #pragma unroll
    for (int i = 0; i < 4; ++i) {
      af[i]  = *(const s16x8*)&As[swz(wr + i*16 + fr, fk)];
      bfv[i] = *(const s16x8*)&Ws[swz(wc + i*16 + fr, fk)];
    }
    #pragma unroll
    for (int i = 0; i < 4; ++i)
      #pragma unroll
      for (int j = 0; j < 4; ++j)
        acc[i][j] = __builtin_amdgcn_mfma_f32_16x16x32_bf16(af[i], bfv[j], acc[i][j], 0, 0, 0);
    __syncthreads();
  }

  int fq = (lane >> 4)*4;
  #pragma unroll
  for (int i = 0; i < 4; ++i) {
    #pragma unroll
    for (int j = 0; j < 4; ++j) {
      size_t row = bm + wr + i*16 + fq;
      size_t col = bn + wc + j*16 + fr;
      #pragma unroll
      for (int qi = 0; qi < 4; ++qi) {
        float val = acc[i][j][qi];
        size_t idx = (row + qi)*(size_t)ldc + col;
        if (EPI == 0) {
          Cf[idx] = val;
        } else if (EPI == 1) {
          Cf[idx] += val;
        } else {
          float uu = U[idx];
          float su = uu / (1.0f + __expf(-uu));
          Cb[idx] = f2bf(su * val);
        }
      }
    }
  }
}

template<int EPI>
__global__ __launch_bounds__(256) void gemm_nt_b(
    const unsigned short* __restrict__ A, const unsigned short* __restrict__ W,
    float* __restrict__ Cf, unsigned short* __restrict__ Cb,
    const float* __restrict__ U, int K, int lda, int ldw, int ldc)
{
  gemm_core_b<EPI>(A, W, Cf, Cb, U, K, lda, ldw, ldc);
}

__global__ __launch_bounds__(256) void gemm_qkv_b(
    const unsigned short* __restrict__ A,
    const unsigned short* __restrict__ Wq, const unsigned short* __restrict__ Wk,
    const unsigned short* __restrict__ Wv,
    float* __restrict__ Cq, float* __restrict__ Ck, float* __restrict__ Cv,
    int K, int lda, int ldw, int ldc)
{
  const unsigned short* W = (blockIdx.z == 0) ? Wq : ((blockIdx.z == 1) ? Wk : Wv);
  float* C                = (blockIdx.z == 0) ? Cq : ((blockIdx.z == 1) ? Ck : Cv);
  gemm_core_b<0>(A, W, C, nullptr, nullptr, K, lda, ldw, ldc);
}

// ---------------- MFMA GEMM, f32 weights (fallback if ws too small) -----------
template<int EPI>
__device__ __forceinline__ void gemm_core_f(
    const unsigned short* __restrict__ A, const float* __restrict__ W,
    float* __restrict__ Cf, unsigned short* __restrict__ Cb,
    const float* __restrict__ U,
    int K, int lda, int ldw, int ldc)
{
  __shared__ unsigned short As[128*32];
  __shared__ unsigned short Ws[128*32];
  int tid = threadIdx.x;
  int lane = tid & 63, wave = tid >> 6;
  int wr = (wave >> 1)*64, wc = (wave & 1)*64;
  size_t bm = (size_t)blockIdx.x * 128, bn = (size_t)blockIdx.y * 128;

  f32x4 acc[4][4];
  #pragma unroll
  for (int i = 0; i < 4; ++i)
    #pragma unroll
    for (int j = 0; j < 4; ++j)
      acc[i][j] = (f32x4){0.f, 0.f, 0.f, 0.f};

  int sr = tid >> 3;
  int sc = (tid & 7) * 4;
  int fr = lane & 15, fk = (lane >> 4)*8;

  for (int kt = 0; kt < K; kt += 32) {
    #pragma unroll
    for (int p = 0; p < 4; ++p) {
      int r = p*32 + sr;
      ushort4 av = *(const ushort4*)(A + (bm + r)*(size_t)lda + kt + sc);
      *(ushort4*)&As[r*32 + sc] = av;
      float4 wv = *(const float4*)(W + (bn + r)*(size_t)ldw + kt + sc);
      ushort4 wb;
      wb.x = f2bf(wv.x); wb.y = f2bf(wv.y); wb.z = f2bf(wv.z); wb.w = f2bf(wv.w);
      *(ushort4*)&Ws[r*32 + sc] = wb;
    }
    __syncthreads();
    s16x8 af[4], bfv[4];
    #pragma unroll
    for (int i = 0; i < 4; ++i) {
      af[i]  = *(const s16x8*)&As[(wr + i*16 + fr)*32 + fk];
      bfv[i] = *(const s16x8*)&Ws[(wc + i*16 + fr)*32 + fk];
    }
    #pragma unroll
    for (int i = 0; i < 4; ++i)
      #pragma unroll
      for (int j = 0; j < 4; ++j)
        acc[i][j] = __builtin_amdgcn_mfma_f32_16x16x32_bf16(af[i], bfv[j], acc[i][j], 0, 0, 0);
    __syncthreads();
  }

  int fq = (lane >> 4)*4;
  #pragma unroll
  for (int i = 0; i < 4; ++i) {
    #pragma unroll
    for (int j = 0; j < 4; ++j) {
      size_t row = bm + wr + i*16 + fq;
      size_t col = bn + wc + j*16 + fr;
      #pragma unroll
      for (int qi = 0; qi < 4; ++qi) {
        float val = acc[i][j][qi];
        size_t idx = (row + qi)*(size_t)ldc + col;
        if (EPI == 0) {
          Cf[idx] = val;
        } else if (EPI == 1) {
          Cf[idx] += val;
        } else {
          float uu = U[idx];
          float su = uu / (1.0f + __expf(-uu));
          Cb[idx] = f2bf(su * val);
        }
      }
    }
  }
}

template<int EPI>
__global__ __launch_bounds__(256) void gemm_nt_f(
    const unsigned short* __restrict__ A, const float* __restrict__ W,
    float* __restrict__ Cf, unsigned short* __restrict__ Cb,
    const float* __restrict__ U, int K, int lda, int ldw, int ldc)
{
  gemm_core_f<EPI>(A, W, Cf, Cb, U, K, lda, ldw, ldc);
}

__global__ __launch_bounds__(256) void gemm_qkv_f(
    const unsigned short* __restrict__ A,
    const float* __restrict__ Wq, const float* __restrict__ Wk, const float* __restrict__ Wv,
    float* __restrict__ Cq, float* __restrict__ Ck, float* __restrict__ Cv,
    int K, int lda, int ldw, int ldc)
{
  const float* W = (blockIdx.z == 0) ? Wq : ((blockIdx.z == 1) ? Wk : Wv);
  float* C       = (blockIdx.z == 0) ? Cq : ((blockIdx.z == 1) ? Ck : Cv);
  gemm_core_f<0>(A, W, C, nullptr, nullptr, K, lda, ldw, ldc);
}

// ---------------- host launcher -----------------------------------------------
extern "C" void kernel_launch(void* const* d_in, const int* in_sizes, int n_in,
                              void* d_out, int out_size, void* d_ws, size_t ws_size,
                              hipStream_t stream)
{
  const int*   tokens    = (const int*)d_in[0];
  const int*   mood      = (const int*)d_in[1];
  const int*   raga      = (const int*)d_in[2];
  const int*   taal      = (const int*)d_in[3];
  const float* tempo     = (const float*)d_in[4];
  const float* duration  = (const float*)d_in[5];
  const int*   tcl       = (const int*)d_in[6];
  const float* tok_emb   = (const float*)d_in[7];
  const float* mood_emb  = (const float*)d_in[8];
  const float* raga_emb  = (const float*)d_in[9];
  const float* taal_emb  = (const float*)d_in[10];
  const float* tempo_w   = (const float*)d_in[11];
  const float* tempo_b   = (const float*)d_in[12];
  const float* dur_w     = (const float*)d_in[13];
  const float* dur_b     = (const float*)d_in[14];
  const float* proj_w    = (const float*)d_in[15];
  const float* proj_b    = (const float*)d_in[16];
  const float* ln_g      = (const float*)d_in[17];
  const float* ln_b      = (const float*)d_in[18];
  const float* cycle_emb = (const float*)d_in[19];
  const float* strength_e= (const float*)d_in[20];
  const float* l_anorm   = (const float*)d_in[21];
  const float* l_fnorm   = (const float*)d_in[22];
  const float* l_q       = (const float*)d_in[23];
  const float* l_k       = (const float*)d_in[24];
  const float* l_v       = (const float*)d_in[25];
  const float* l_o       = (const float*)d_in[26];
  const float* l_w1      = (const float*)d_in[27];
  const float* l_w2      = (const float*)d_in[28];
  const float* l_w3      = (const float*)d_in[29];
  const float* final_norm= (const float*)d_in[30];
  const float* head_w    = (const float*)d_in[31];

  size_t off = 0;
  char* wsb = (char*)d_ws;
  auto alloc = [&](size_t bytes) -> char* {
    char* p = wsb + off;
    off += (bytes + 255) & ~(size_t)255;
    return p;
  };
  float*          condb  = (float*)alloc((size_t)B_*D_*4);
  float*          costab = (float*)alloc((size_t)S_*HD_*4);
  float*          sintab = (float*)alloc((size_t)S_*HD_*4);
  float*          x      = (float*)alloc((size_t)B_*S_*D_*4);
  unsigned short* hbuf   = (unsigned short*)alloc((size_t)B_*S_*D_*2);
  float*          qb     = (float*)alloc((size_t)B_*S_*D_*4);
  float*          kb     = (float*)alloc((size_t)B_*S_*D_*4);
  float*          vb     = (float*)alloc((size_t)B_*S_*D_*4);
  unsigned short* yb     = (unsigned short*)alloc((size_t)B_*S_*D_*2);
  float*          ub     = (float*)alloc((size_t)B_*S_*FF_*4);
  unsigned short* tb     = (unsigned short*)alloc((size_t)B_*S_*FF_*2);

  // bf16 weight cache layout (elements)
  const size_t N_QKVO = (size_t)L_*D_*D_;       // 8,388,608 per tensor
  const size_t N_FF   = (size_t)L_*FF_*D_;      // 33,554,432 per tensor
  const size_t N_HEAD = (size_t)V_*D_;          // 2,097,152
  const size_t W_TOT  = 4*N_QKVO + 3*N_FF + N_HEAD;
  size_t off_before_w = off;
  unsigned short* wbf = (unsigned short*)alloc(W_TOT*2);
  bool use_bf16 = (off <= ws_size);
  if (!use_bf16) off = off_before_w;

  rope_table_kernel<<<(S_*HD_)/256, 256, 0, stream>>>(costab, sintab);
  cond_kernel<<<B_, 256, 0, stream>>>(mood, raga, taal, tempo, duration,
      mood_emb, raga_emb, taal_emb, tempo_w, tempo_b, dur_w, dur_b,
      proj_w, proj_b, ln_g, ln_b, condb);
  embed_kernel<<<B_*S_, 256, 0, stream>>>(tokens, tok_emb, condb, cycle_emb,
      strength_e, tcl, x);

  const int rows = B_*S_;   // 2048
  if (use_bf16) {
    unsigned short* bq = wbf;
    unsigned short* bk = wbf + N_QKVO;
    unsigned short* bv = wbf + 2*N_QKVO;
    unsigned short* bo = wbf + 3*N_QKVO;
    unsigned short* b1 = wbf + 4*N_QKVO;
    unsigned short* b2 = wbf + 4*N_QKVO + N_FF;
    unsigned short* b3 = wbf + 4*N_QKVO + 2*N_FF;
    unsigned short* bh = wbf + 4*N_QKVO + 3*N_FF;
    cvt_kernel<<<(int)(N_QKVO/8/256), 256, 0, stream>>>(l_q,  bq, (int)(N_QKVO/8));
    cvt_kernel<<<(int)(N_QKVO/8/256), 256, 0, stream>>>(l_k,  bk, (int)(N_QKVO/8));
    cvt_kernel<<<(int)(N_QKVO/8/256), 256, 0, stream>>>(l_v,  bv, (int)(N_QKVO/8));
    cvt_kernel<<<(int)(N_QKVO/8/256), 256, 0, stream>>>(l_o,  bo, (int)(N_QKVO/8));
    cvt_kernel<<<(int)(N_FF/8/256),   256, 0, stream>>>(l_w1, b1, (int)(N_FF/8));
    cvt_kernel<<<(int)(N_FF/8/256),   256, 0, stream>>>(l_w2, b2, (int)(N_FF/8));
    cvt_kernel<<<(int)(N_FF/8/256),   256, 0, stream>>>(l_w3, b3, (int)(N_FF/8));
    cvt_kernel<<<(int)(N_HEAD/8/256), 256, 0, stream>>>(head_w, bh, (int)(N_HEAD/8));

    for (int l = 0; l < L_; ++l) {
      size_t dd = (size_t)l*D_*D_;
      size_t fd = (size_t)l*FF_*D_;
      rmsnorm_kernel<<<rows, 256, 0, stream>>>(x, l_anorm + (size_t)l*D_, hbuf);
      gemm_qkv_b<<<dim3(rows/128, D_/128, 3), 256, 0, stream>>>(
          hbuf, bq + dd, bk + dd, bv + dd, qb, kb, vb, D_, D_, D_, D_);
      rope_kernel<<<dim3((rows*512)/256, 2), 256, 0, stream>>>(qb, kb, costab, sintab);
      attn_kernel<<<dim3(S_/64, H_, B_), 256, 0, stream>>>(qb, kb, vb, yb);
      gemm_nt_b<1><<<dim3(rows/128, D_/128), 256, 0, stream>>>(
          yb, bo + dd, x, nullptr, nullptr, D_, D_, D_, D_);
      rmsnorm_kernel<<<rows, 256, 0, stream>>>(x, l_fnorm + (size_t)l*D_, hbuf);
      gemm_nt_b<0><<<dim3(rows/128, FF_/128), 256, 0, stream>>>(
          hbuf, b1 + fd, ub, nullptr, nullptr, D_, D_, D_, FF_);
      gemm_nt_b<2><<<dim3(rows/128, FF_/128), 256, 0, stream>>>(
          hbuf, b3 + fd, nullptr, tb, ub, D_, D_, D_, FF_);
      gemm_nt_b<1><<<dim3(rows/128, D_/128), 256, 0, stream>>>(
          tb, b2 + fd, x, nullptr, nullptr, FF_, FF_, FF_, D_);
    }
    rmsnorm_kernel<<<rows, 256, 0, stream>>>(x, final_norm, hbuf);
    gemm_nt_b<0><<<dim3(rows/128, V_/128), 256, 0, stream>>>(
        hbuf, bh, (float*)d_out, nullptr, nullptr, D_, D_, D_, V_);
  } else {
    for (int l = 0; l < L_; ++l) {
      size_t dd = (size_t)l*D_*D_;
      size_t fd = (size_t)l*FF_*D_;
      rmsnorm_kernel<<<rows, 256, 0, stream>>>(x, l_anorm + (size_t)l*D_, hbuf);
      gemm_qkv_f<<<dim3(rows/128, D_/128, 3), 256, 0, stream>>>(
          hbuf, l_q + dd, l_k + dd, l_v + dd, qb, kb, vb, D_, D_, D_, D_);
      rope_kernel<<<dim3((rows*512)/256, 2), 256, 0, stream>>>(qb, kb, costab, sintab);
      attn_kernel<<<dim3(S_/64, H_, B_), 256, 0, stream>>>(qb, kb, vb, yb);
      gemm_nt_f<1><<<dim3(rows/128, D_/128), 256, 0, stream>>>(
          yb, l_o + dd, x, nullptr, nullptr, D_, D_, D_, D_);
      rmsnorm_kernel<<<rows, 256, 0, stream>>>(x, l_fnorm + (size_t)l*D_, hbuf);
      gemm_nt_f<0><<<dim3(rows/128, FF_/128), 256, 0, stream>>>(
          hbuf, l_w1 + fd, ub, nullptr, nullptr, D_, D_, D_, FF_);
      gemm_nt_f<2><<<dim3(rows/128, FF_/128), 256, 0, stream>>>(
          hbuf, l_w3 + fd, nullptr, tb, ub, D_, D_, D_, FF_);
      gemm_nt_f<1><<<dim3(rows/128, D_/128), 256, 0, stream>>>(
          tb, l_w2 + (size_t)l*D_*FF_, x, nullptr, nullptr, FF_, FF_, FF_, D_);
    }
    rmsnorm_kernel<<<rows, 256, 0, stream>>>(x, final_norm, hbuf);
    gemm_nt_f<0><<<dim3(rows/128, V_/128), 256, 0, stream>>>(
        hbuf, head_w, (float*)d_out, nullptr, nullptr, D_, D_, D_, V_);
  }
}

// Round 3
// 2629.699 us; speedup vs baseline: 2.0040x; 1.2458x over previous
//
#include <hip/hip_runtime.h>
#include <math.h>

#define D_ 1024
#define H_ 16
#define HD_ 64
#define L_ 8
#define V_ 2048
#define FF_ 4096
#define WIN_ 256
#define B_ 2
#define S_ 1024
#define MAXCYC_ 16

typedef __attribute__((ext_vector_type(4))) float f32x4;
typedef __attribute__((ext_vector_type(8))) short s16x8;

__device__ __forceinline__ unsigned short f2bf(float f) {
  union { float f; unsigned int u; } v; v.f = f;
  unsigned int r = v.u + 0x7FFFu + ((v.u >> 16) & 1u);
  return (unsigned short)(r >> 16);
}

__device__ __forceinline__ float wave_sum(float v) {
  #pragma unroll
  for (int m = 1; m < 64; m <<= 1) v += __shfl_xor(v, m, 64);
  return v;
}

// async global->LDS, 16B per lane. dst must be wave-uniform base; HW writes
// dst + lane*16. Source is per-lane.
__device__ __forceinline__ void gload16(const unsigned short* g, unsigned short* lds) {
  __builtin_amdgcn_global_load_lds(
      (const __attribute__((address_space(1))) void*)g,
      (__attribute__((address_space(3))) void*)lds,
      16, 0, 0);
}

// ---------------- f32 -> bf16 convert (weights) ------------------------------
__global__ __launch_bounds__(256) void cvt_kernel(
    const float* __restrict__ src, unsigned short* __restrict__ dst, int n8)
{
  int i = blockIdx.x*256 + threadIdx.x;
  if (i >= n8) return;
  const float4* s = (const float4*)src + (size_t)i*2;
  float4 a = s[0], b = s[1];
  ushort4 lo, hi;
  lo.x = f2bf(a.x); lo.y = f2bf(a.y); lo.z = f2bf(a.z); lo.w = f2bf(a.w);
  hi.x = f2bf(b.x); hi.y = f2bf(b.y); hi.z = f2bf(b.z); hi.w = f2bf(b.w);
  *(ushort4*)(dst + (size_t)i*8)     = lo;
  *(ushort4*)(dst + (size_t)i*8 + 4) = hi;
}

// ---------------- conditioning ----------------------------------------------
__global__ __launch_bounds__(256) void cond_kernel(
    const int* mood, const int* raga, const int* taal,
    const float* tempo, const float* duration,
    const float* mood_emb, const float* raga_emb, const float* taal_emb,
    const float* tempo_w, const float* tempo_b, const float* dur_w, const float* dur_b,
    const float* proj_w, const float* proj_b, const float* ln_g, const float* ln_b,
    float* cond)
{
  int b = blockIdx.x;
  int t = threadIdx.x;
  __shared__ float feat[192];
  __shared__ float red[4];
  if (t < 64)        feat[t] = mood_emb[mood[b]*64 + t];
  else if (t < 128)  feat[t] = raga_emb[raga[b]*64 + (t-64)];
  else if (t < 160)  feat[t] = taal_emb[taal[b]*32 + (t-128)];
  else if (t < 176)  feat[t] = tempo[b]*tempo_w[t-160] + tempo_b[t-160];
  else if (t < 192)  feat[t] = duration[b]*dur_w[t-176] + dur_b[t-176];
  __syncthreads();
  float g[4];
  #pragma unroll
  for (int r = 0; r < 4; ++r) {
    int j = t + 256*r;
    const float* w = proj_w + (size_t)j*192;
    float acc = proj_b[j];
    for (int f = 0; f < 192; ++f) acc += feat[f]*w[f];
    g[r] = 0.5f * acc * (1.0f + erff(acc * 0.7071067811865475f));
  }
  int lane = t & 63, wv = t >> 6;
  float s1 = g[0]+g[1]+g[2]+g[3];
  s1 = wave_sum(s1);
  if (lane == 0) red[wv] = s1;
  __syncthreads();
  float mu = (red[0]+red[1]+red[2]+red[3]) * (1.0f/1024.0f);
  __syncthreads();
  float vs = 0.f;
  #pragma unroll
  for (int r = 0; r < 4; ++r) { float d = g[r]-mu; vs += d*d; }
  vs = wave_sum(vs);
  if (lane == 0) red[wv] = vs;
  __syncthreads();
  float var = (red[0]+red[1]+red[2]+red[3]) * (1.0f/1024.0f);
  float is = rsqrtf(var + 1e-5f);
  #pragma unroll
  for (int r = 0; r < 4; ++r) {
    int j = t + 256*r;
    cond[(size_t)b*D_ + j] = (g[r]-mu)*is*ln_g[j] + ln_b[j];
  }
}

// ---------------- embedding sum ----------------------------------------------
__global__ __launch_bounds__(256) void embed_kernel(
    const int* tokens, const float* tok_emb, const float* cond,
    const float* cycle_emb, const float* strength_emb, const int* tcl_p, float* x)
{
  int row = blockIdx.x;
  int b = row >> 10, s = row & 1023;
  int tcl = tcl_p[0];
  int cyc = tcl < MAXCYC_ ? tcl : MAXCYC_;
  int pr  = s % cyc;
  int str = (s % tcl == 0) ? 0 : 3;
  int tok = tokens[row];
  int d = threadIdx.x * 4;
  float4 a = *(const float4*)&tok_emb[(size_t)tok*D_ + d];
  float4 c = *(const float4*)&cond[(size_t)b*D_ + d];
  float4 p = *(const float4*)&cycle_emb[(size_t)pr*D_ + d];
  float4 e = *(const float4*)&strength_emb[(size_t)str*D_ + d];
  float4 o; o.x=a.x+c.x+p.x+e.x; o.y=a.y+c.y+p.y+e.y; o.z=a.z+c.z+p.z+e.z; o.w=a.w+c.w+p.w+e.w;
  *(float4*)&x[(size_t)row*D_ + d] = o;
}

// ---------------- rmsnorm -> bf16 --------------------------------------------
__global__ __launch_bounds__(256) void rmsnorm_kernel(
    const float* x, const float* w, unsigned short* out)
{
  int row = blockIdx.x;
  int t = threadIdx.x;
  __shared__ float red[4];
  const float* xr = x + (size_t)row*D_;
  float4 v = *(const float4*)&xr[t*4];
  float ss = v.x*v.x + v.y*v.y + v.z*v.z + v.w*v.w;
  ss = wave_sum(ss);
  int lane = t & 63, wv = t >> 6;
  if (lane == 0) red[wv] = ss;
  __syncthreads();
  float total = red[0]+red[1]+red[2]+red[3];
  float scale = rsqrtf(total * (1.0f/1024.0f) + 1e-5f);
  float4 wv4 = *(const float4*)&w[t*4];
  ushort4 o;
  o.x = f2bf(wv4.x * v.x * scale);
  o.y = f2bf(wv4.y * v.y * scale);
  o.z = f2bf(wv4.z * v.z * scale);
  o.w = f2bf(wv4.w * v.w * scale);
  *(ushort4*)&out[(size_t)row*D_ + t*4] = o;
}

// ---------------- rope tables -------------------------------------------------
__global__ __launch_bounds__(256) void rope_table_kernel(float* costab, float* sintab)
{
  int i = blockIdx.x*256 + threadIdx.x;
  int s = i >> 6, d = i & 63;
  float inv = powf(10000.0f, -(float)(d & 31) * (1.0f/32.0f));
  float ang = (float)s * inv;
  float sn, cs;
  sincosf(ang, &sn, &cs);
  costab[i] = cs; sintab[i] = sn;
}

// ---------------- sliding-window flash attention (4 threads / query) ----------
#define KPAD_ 68
__global__ __launch_bounds__(256) void attn_kernel(
    const float* __restrict__ q, const float* __restrict__ k,
    const float* __restrict__ v, unsigned short* __restrict__ y)
{
  __shared__ float Ks[64*KPAD_];
  __shared__ float Vs[64*KPAD_];
  int qb0 = blockIdx.x * 64;
  int h  = blockIdx.y;
  int b  = blockIdx.z;
  int t  = threadIdx.x;
  int ql = t >> 2;
  int dp = (t & 3) * 16;
  int s  = qb0 + ql;

  const float* qrow = q + ((size_t)(b*S_ + s)*D_ + h*HD_ + dp);
  float qr[16];
  #pragma unroll
  for (int i = 0; i < 4; ++i) {
    float4 tmp = *(const float4*)&qrow[i*4];
    qr[i*4+0]=tmp.x; qr[i*4+1]=tmp.y; qr[i*4+2]=tmp.z; qr[i*4+3]=tmp.w;
  }
  float acc[16];
  #pragma unroll
  for (int i = 0; i < 16; ++i) acc[i] = 0.f;
  float m = -1e30f, l = 0.f;

  int lo = qb0 - (WIN_-1); if (lo < 0) lo = 0;
  int kt0 = lo & ~63;
  int sr = t >> 2;
  int sc = (t & 3) * 16;

  for (int kt = kt0; kt <= qb0 + 63; kt += 64) {
    __syncthreads();
    size_t srcb = (size_t)(b*S_ + kt + sr)*D_ + h*HD_ + sc;
    #pragma unroll
    for (int i = 0; i < 4; ++i) {
      *(float4*)&Ks[sr*KPAD_ + sc + i*4] = *(const float4*)&k[srcb + i*4];
      *(float4*)&Vs[sr*KPAD_ + sc + i*4] = *(const float4*)&v[srcb + i*4];
    }
    __syncthreads();
    int jmax = s - kt;              if (jmax > 63) jmax = 63;
    int jmin = (s - (WIN_-1)) - kt; if (jmin < 0) jmin = 0;
    for (int j = jmin; j <= jmax; ++j) {
      const float* kr = &Ks[j*KPAD_ + dp];
      float dot = 0.f;
      #pragma unroll
      for (int i = 0; i < 4; ++i) {
        float4 kv = *(const float4*)&kr[i*4];
        dot += qr[i*4]*kv.x + qr[i*4+1]*kv.y + qr[i*4+2]*kv.z + qr[i*4+3]*kv.w;
      }
      dot += __shfl_xor(dot, 1, 64);
      dot += __shfl_xor(dot, 2, 64);
      float sc2 = dot * 0.125f;
      if (sc2 > m) {
        float f = __expf(m - sc2);
        #pragma unroll
        for (int i = 0; i < 16; ++i) acc[i] *= f;
        l *= f; m = sc2;
      }
      float p = __expf(sc2 - m);
      l += p;
      const float* vr = &Vs[j*KPAD_ + dp];
      #pragma unroll
      for (int i = 0; i < 4; ++i) {
        float4 vv = *(const float4*)&vr[i*4];
        acc[i*4+0] += p*vv.x; acc[i*4+1] += p*vv.y;
        acc[i*4+2] += p*vv.z; acc[i*4+3] += p*vv.w;
      }
    }
  }
  float inv = 1.0f / l;
  unsigned short* yr = y + ((size_t)(b*S_ + s)*D_ + h*HD_ + dp);
  #pragma unroll
  for (int i = 0; i < 4; ++i) {
    ushort4 o;
    o.x = f2bf(acc[i*4+0]*inv); o.y = f2bf(acc[i*4+1]*inv);
    o.z = f2bf(acc[i*4+2]*inv); o.w = f2bf(acc[i*4+3]*inv);
    *(ushort4*)&yr[i*4] = o;
  }
}

// =============== fused W1/W3 GEMM: 128x128 tile, dual accumulator =============
// T[M,FF](bf16) = silu(A*W1^T) * (A*W3^T); A bf16 [M,K], W* bf16 [FF,K].
// double-buffered LDS + global_load_lds; prefetch next K-tile before compute.
__global__ __launch_bounds__(256, 2) void gemm_w13(
    const unsigned short* __restrict__ A,
    const unsigned short* __restrict__ W1, const unsigned short* __restrict__ W3,
    unsigned short* __restrict__ T, int K, int lda, int ldw)
{
  __shared__ unsigned short sA[2][128*32];
  __shared__ unsigned short sW1[2][128*32];
  __shared__ unsigned short sW3[2][128*32];
  int tid = threadIdx.x, lane = tid & 63, wave = tid >> 6;
  int wr = (wave >> 1)*64, wc = (wave & 1)*64;
  size_t bm = (size_t)blockIdx.x*128, bn = (size_t)blockIdx.y*128;
  int fr = lane & 15, fk = (lane >> 4)*8, fq = (lane >> 4)*4;
  int rseg = lane >> 2, chunk = (lane & 3)*8;

  f32x4 a1[4][4], a3[4][4];
  #pragma unroll
  for (int i = 0; i < 4; ++i)
    #pragma unroll
    for (int j = 0; j < 4; ++j) {
      a1[i][j] = (f32x4){0.f,0.f,0.f,0.f};
      a3[i][j] = (f32x4){0.f,0.f,0.f,0.f};
    }

  auto stage = [&](int buf, int kt) {
    #pragma unroll
    for (int p = 0; p < 2; ++p) {
      int seg = wave*2 + p;
      int row = seg*16 + rseg;
      gload16(A  + (bm + row)*(size_t)lda + kt + chunk, &sA[buf][seg*512]);
      gload16(W1 + (bn + row)*(size_t)ldw + kt + chunk, &sW1[buf][seg*512]);
      gload16(W3 + (bn + row)*(size_t)ldw + kt + chunk, &sW3[buf][seg*512]);
    }
  };

  stage(0, 0);
  __syncthreads();
  int nt = K >> 5;
  for (int t = 0; t < nt; ++t) {
    int cur = t & 1;
    if (t + 1 < nt) stage(cur ^ 1, (t+1)*32);
    s16x8 af[4], b1[4], b3[4];
    #pragma unroll
    for (int i = 0; i < 4; ++i) {
      af[i] = *(const s16x8*)&sA[cur][(wr + i*16 + fr)*32 + fk];
      b1[i] = *(const s16x8*)&sW1[cur][(wc + i*16 + fr)*32 + fk];
      b3[i] = *(const s16x8*)&sW3[cur][(wc + i*16 + fr)*32 + fk];
    }
    #pragma unroll
    for (int i = 0; i < 4; ++i)
      #pragma unroll
      for (int j = 0; j < 4; ++j) {
        a1[i][j] = __builtin_amdgcn_mfma_f32_16x16x32_bf16(af[i], b1[j], a1[i][j], 0, 0, 0);
        a3[i][j] = __builtin_amdgcn_mfma_f32_16x16x32_bf16(af[i], b3[j], a3[i][j], 0, 0, 0);
      }
    __syncthreads();
  }

  #pragma unroll
  for (int i = 0; i < 4; ++i)
    #pragma unroll
    for (int j = 0; j < 4; ++j) {
      size_t row0 = bm + wr + i*16 + fq;
      size_t col  = bn + wc + j*16 + fr;
      #pragma unroll
      for (int qi = 0; qi < 4; ++qi) {
        float u = a1[i][j][qi];
        float g = a3[i][j][qi];
        float su = u / (1.0f + __expf(-u));
        T[(row0 + qi)*(size_t)FF_ + col] = f2bf(su * g);
      }
    }
}

// =============== generic GEMM: 128x64 tile ====================================
// C[M,N] = A[M,K](bf16) * W[N,K](bf16)^T. 4 waves 2x2, each 64x32.
// EPI: 0 = store f32, 1 = add into f32, 2 = rope-store f32 (q/k)
template<int EPI>
__device__ __forceinline__ void gemm64_core(
    const unsigned short* __restrict__ A, const unsigned short* __restrict__ W,
    float* __restrict__ Cf, int K, int lda, int ldw, int ldc,
    const float* __restrict__ costab, const float* __restrict__ sintab)
{
  __shared__ unsigned short sA[2][128*32];
  __shared__ unsigned short sW[2][64*32];
  int tid = threadIdx.x, lane = tid & 63, wave = tid >> 6;
  int wr = (wave >> 1)*64, wc = (wave & 1)*32;
  size_t bm = (size_t)blockIdx.x*128, bn = (size_t)blockIdx.y*64;
  int fr = lane & 15, fk = (lane >> 4)*8, fq = (lane >> 4)*4;
  int rseg = lane >> 2, chunk = (lane & 3)*8;

  f32x4 acc[4][2];
  #pragma unroll
  for (int i = 0; i < 4; ++i) {
    acc[i][0] = (f32x4){0.f,0.f,0.f,0.f};
    acc[i][1] = (f32x4){0.f,0.f,0.f,0.f};
  }

  auto stage = [&](int buf, int kt) {
    #pragma unroll
    for (int p = 0; p < 2; ++p) {
      int seg = wave*2 + p;
      int row = seg*16 + rseg;
      gload16(A + (bm + row)*(size_t)lda + kt + chunk, &sA[buf][seg*512]);
    }
    int row = wave*16 + rseg;
    gload16(W + (bn + row)*(size_t)ldw + kt + chunk, &sW[buf][wave*512]);
  };

  stage(0, 0);
  __syncthreads();
  int nt = K >> 5;
  for (int t = 0; t < nt; ++t) {
    int cur = t & 1;
    if (t + 1 < nt) stage(cur ^ 1, (t+1)*32);
    s16x8 af[4], bw[2];
    #pragma unroll
    for (int i = 0; i < 4; ++i)
      af[i] = *(const s16x8*)&sA[cur][(wr + i*16 + fr)*32 + fk];
    #pragma unroll
    for (int j = 0; j < 2; ++j)
      bw[j] = *(const s16x8*)&sW[cur][(wc + j*16 + fr)*32 + fk];
    #pragma unroll
    for (int i = 0; i < 4; ++i)
      #pragma unroll
      for (int j = 0; j < 2; ++j)
        acc[i][j] = __builtin_amdgcn_mfma_f32_16x16x32_bf16(af[i], bw[j], acc[i][j], 0, 0, 0);
    __syncthreads();
  }

  #pragma unroll
  for (int i = 0; i < 4; ++i)
    #pragma unroll
    for (int j = 0; j < 2; ++j) {
      size_t row0 = bm + wr + i*16 + fq;
      size_t col  = bn + wc + j*16 + fr;
      #pragma unroll
      for (int qi = 0; qi < 4; ++qi) {
        float val = acc[i][j][qi];
        size_t idx = (row0 + qi)*(size_t)ldc + col;
        if (EPI == 2) {
          float pv = __shfl_xor(val, 1, 64);
          int srow = (int)((row0 + qi) & 1023);
          int d = (int)(col & 63);
          float cs = costab[srow*64 + d];
          float sn = sintab[srow*64 + d];
          Cf[idx] = val*cs + ((d & 1) ? pv : -pv)*sn;
        } else if (EPI == 1) {
          Cf[idx] += val;
        } else {
          Cf[idx] = val;
        }
      }
    }
}

template<int EPI>
__global__ __launch_bounds__(256) void gemm64(
    const unsigned short* __restrict__ A, const unsigned short* __restrict__ W,
    float* __restrict__ Cf, int K, int lda, int ldw, int ldc)
{
  gemm64_core<EPI>(A, W, Cf, K, lda, ldw, ldc, nullptr, nullptr);
}

__global__ __launch_bounds__(256) void gemm_qkv64(
    const unsigned short* __restrict__ A,
    const unsigned short* __restrict__ Wq, const unsigned short* __restrict__ Wk,
    const unsigned short* __restrict__ Wv,
    float* __restrict__ Cq, float* __restrict__ Ck, float* __restrict__ Cv,
    const float* __restrict__ costab, const float* __restrict__ sintab)
{
  const unsigned short* W = (blockIdx.z == 0) ? Wq : ((blockIdx.z == 1) ? Wk : Wv);
  float* C                = (blockIdx.z == 0) ? Cq : ((blockIdx.z == 1) ? Ck : Cv);
  if (blockIdx.z < 2)
    gemm64_core<2>(A, W, C, D_, D_, D_, D_, costab, sintab);
  else
    gemm64_core<0>(A, W, C, D_, D_, D_, D_, nullptr, nullptr);
}

// ---------------- host launcher -----------------------------------------------
extern "C" void kernel_launch(void* const* d_in, const int* in_sizes, int n_in,
                              void* d_out, int out_size, void* d_ws, size_t ws_size,
                              hipStream_t stream)
{
  const int*   tokens    = (const int*)d_in[0];
  const int*   mood      = (const int*)d_in[1];
  const int*   raga      = (const int*)d_in[2];
  const int*   taal      = (const int*)d_in[3];
  const float* tempo     = (const float*)d_in[4];
  const float* duration  = (const float*)d_in[5];
  const int*   tcl       = (const int*)d_in[6];
  const float* tok_emb   = (const float*)d_in[7];
  const float* mood_emb  = (const float*)d_in[8];
  const float* raga_emb  = (const float*)d_in[9];
  const float* taal_emb  = (const float*)d_in[10];
  const float* tempo_w   = (const float*)d_in[11];
  const float* tempo_b   = (const float*)d_in[12];
  const float* dur_w     = (const float*)d_in[13];
  const float* dur_b     = (const float*)d_in[14];
  const float* proj_w    = (const float*)d_in[15];
  const float* proj_b    = (const float*)d_in[16];
  const float* ln_g      = (const float*)d_in[17];
  const float* ln_b      = (const float*)d_in[18];
  const float* cycle_emb = (const float*)d_in[19];
  const float* strength_e= (const float*)d_in[20];
  const float* l_anorm   = (const float*)d_in[21];
  const float* l_fnorm   = (const float*)d_in[22];
  const float* l_q       = (const float*)d_in[23];
  const float* l_k       = (const float*)d_in[24];
  const float* l_v       = (const float*)d_in[25];
  const float* l_o       = (const float*)d_in[26];
  const float* l_w1      = (const float*)d_in[27];
  const float* l_w2      = (const float*)d_in[28];
  const float* l_w3      = (const float*)d_in[29];
  const float* final_norm= (const float*)d_in[30];
  const float* head_w    = (const float*)d_in[31];

  size_t off = 0;
  char* wsb = (char*)d_ws;
  auto alloc = [&](size_t bytes) -> char* {
    char* p = wsb + off;
    off += (bytes + 255) & ~(size_t)255;
    return p;
  };
  float*          condb  = (float*)alloc((size_t)B_*D_*4);
  float*          costab = (float*)alloc((size_t)S_*HD_*4);
  float*          sintab = (float*)alloc((size_t)S_*HD_*4);
  float*          x      = (float*)alloc((size_t)B_*S_*D_*4);
  unsigned short* hbuf   = (unsigned short*)alloc((size_t)B_*S_*D_*2);
  float*          qb     = (float*)alloc((size_t)B_*S_*D_*4);
  float*          kb     = (float*)alloc((size_t)B_*S_*D_*4);
  float*          vb     = (float*)alloc((size_t)B_*S_*D_*4);
  unsigned short* yb     = (unsigned short*)alloc((size_t)B_*S_*D_*2);
  unsigned short* tb     = (unsigned short*)alloc((size_t)B_*S_*FF_*2);

  const size_t N_QKVO = (size_t)L_*D_*D_;
  const size_t N_FF   = (size_t)L_*FF_*D_;
  const size_t N_HEAD = (size_t)V_*D_;
  unsigned short* wbf = (unsigned short*)alloc((4*N_QKVO + 3*N_FF + N_HEAD)*2);
  unsigned short* bq = wbf;
  unsigned short* bk = wbf + N_QKVO;
  unsigned short* bv = wbf + 2*N_QKVO;
  unsigned short* bo = wbf + 3*N_QKVO;
  unsigned short* b1 = wbf + 4*N_QKVO;
  unsigned short* b2 = wbf + 4*N_QKVO + N_FF;
  unsigned short* b3 = wbf + 4*N_QKVO + 2*N_FF;
  unsigned short* bh = wbf + 4*N_QKVO + 3*N_FF;

  rope_table_kernel<<<(S_*HD_)/256, 256, 0, stream>>>(costab, sintab);
  cond_kernel<<<B_, 256, 0, stream>>>(mood, raga, taal, tempo, duration,
      mood_emb, raga_emb, taal_emb, tempo_w, tempo_b, dur_w, dur_b,
      proj_w, proj_b, ln_g, ln_b, condb);
  embed_kernel<<<B_*S_, 256, 0, stream>>>(tokens, tok_emb, condb, cycle_emb,
      strength_e, tcl, x);

  cvt_kernel<<<(int)(N_QKVO/8/256), 256, 0, stream>>>(l_q,  bq, (int)(N_QKVO/8));
  cvt_kernel<<<(int)(N_QKVO/8/256), 256, 0, stream>>>(l_k,  bk, (int)(N_QKVO/8));
  cvt_kernel<<<(int)(N_QKVO/8/256), 256, 0, stream>>>(l_v,  bv, (int)(N_QKVO/8));
  cvt_kernel<<<(int)(N_QKVO/8/256), 256, 0, stream>>>(l_o,  bo, (int)(N_QKVO/8));
  cvt_kernel<<<(int)(N_FF/8/256),   256, 0, stream>>>(l_w1, b1, (int)(N_FF/8));
  cvt_kernel<<<(int)(N_FF/8/256),   256, 0, stream>>>(l_w2, b2, (int)(N_FF/8));
  cvt_kernel<<<(int)(N_FF/8/256),   256, 0, stream>>>(l_w3, b3, (int)(N_FF/8));
  cvt_kernel<<<(int)(N_HEAD/8/256), 256, 0, stream>>>(head_w, bh, (int)(N_HEAD/8));

  const int rows = B_*S_;   // 2048
  for (int l = 0; l < L_; ++l) {
    size_t dd = (size_t)l*D_*D_;
    size_t fd = (size_t)l*FF_*D_;
    rmsnorm_kernel<<<rows, 256, 0, stream>>>(x, l_anorm + (size_t)l*D_, hbuf);
    gemm_qkv64<<<dim3(rows/128, D_/64, 3), 256, 0, stream>>>(
        hbuf, bq + dd, bk + dd, bv + dd, qb, kb, vb, costab, sintab);
    attn_kernel<<<dim3(S_/64, H_, B_), 256, 0, stream>>>(qb, kb, vb, yb);
    gemm64<1><<<dim3(rows/128, D_/64), 256, 0, stream>>>(
        yb, bo + dd, x, D_, D_, D_, D_);
    rmsnorm_kernel<<<rows, 256, 0, stream>>>(x, l_fnorm + (size_t)l*D_, hbuf);
    gemm_w13<<<dim3(rows/128, FF_/128), 256, 0, stream>>>(
        hbuf, b1 + fd, b3 + fd, tb, D_, D_, D_);
    gemm64<1><<<dim3(rows/128, D_/64), 256, 0, stream>>>(
        tb, b2 + fd, x, FF_, FF_, FF_, D_);
  }
  rmsnorm_kernel<<<rows, 256, 0, stream>>>(x, final_norm, hbuf);
  gemm64<0><<<dim3(rows/128, V_/64), 256, 0, stream>>>(
      hbuf, bh, (float*)d_out, D_, D_, D_, V_);
}

// Round 4
// 1897.724 us; speedup vs baseline: 2.7770x; 1.3857x over previous
//
#include <hip/hip_runtime.h>
#include <math.h>

#define D_ 1024
#define H_ 16
#define HD_ 64
#define L_ 8
#define V_ 2048
#define FF_ 4096
#define WIN_ 256
#define B_ 2
#define S_ 1024
#define MAXCYC_ 16

typedef __attribute__((ext_vector_type(4))) float f32x4;
typedef __attribute__((ext_vector_type(8))) short s16x8;

__device__ __forceinline__ unsigned short f2bf(float f) {
  union { float f; unsigned int u; } v; v.f = f;
  unsigned int r = v.u + 0x7FFFu + ((v.u >> 16) & 1u);
  return (unsigned short)(r >> 16);
}

__device__ __forceinline__ float wave_sum(float v) {
  #pragma unroll
  for (int m = 1; m < 64; m <<= 1) v += __shfl_xor(v, m, 64);
  return v;
}

// async global->LDS, 16B per lane. dst wave-uniform base; HW writes dst+lane*16.
__device__ __forceinline__ void gload16(const unsigned short* g, unsigned short* lds) {
  __builtin_amdgcn_global_load_lds(
      (const __attribute__((address_space(1))) void*)g,
      (__attribute__((address_space(3))) void*)lds,
      16, 0, 0);
}

// ---------------- f32 -> bf16 convert (weights) ------------------------------
__global__ __launch_bounds__(256) void cvt_kernel(
    const float* __restrict__ src, unsigned short* __restrict__ dst, int n8)
{
  int i = blockIdx.x*256 + threadIdx.x;
  if (i >= n8) return;
  const float4* s = (const float4*)src + (size_t)i*2;
  float4 a = s[0], b = s[1];
  ushort4 lo, hi;
  lo.x = f2bf(a.x); lo.y = f2bf(a.y); lo.z = f2bf(a.z); lo.w = f2bf(a.w);
  hi.x = f2bf(b.x); hi.y = f2bf(b.y); hi.z = f2bf(b.z); hi.w = f2bf(b.w);
  *(ushort4*)(dst + (size_t)i*8)     = lo;
  *(ushort4*)(dst + (size_t)i*8 + 4) = hi;
}

// ---------------- conditioning ----------------------------------------------
__global__ __launch_bounds__(256) void cond_kernel(
    const int* mood, const int* raga, const int* taal,
    const float* tempo, const float* duration,
    const float* mood_emb, const float* raga_emb, const float* taal_emb,
    const float* tempo_w, const float* tempo_b, const float* dur_w, const float* dur_b,
    const float* proj_w, const float* proj_b, const float* ln_g, const float* ln_b,
    float* cond)
{
  int b = blockIdx.x;
  int t = threadIdx.x;
  __shared__ float feat[192];
  __shared__ float red[4];
  if (t < 64)        feat[t] = mood_emb[mood[b]*64 + t];
  else if (t < 128)  feat[t] = raga_emb[raga[b]*64 + (t-64)];
  else if (t < 160)  feat[t] = taal_emb[taal[b]*32 + (t-128)];
  else if (t < 176)  feat[t] = tempo[b]*tempo_w[t-160] + tempo_b[t-160];
  else if (t < 192)  feat[t] = duration[b]*dur_w[t-176] + dur_b[t-176];
  __syncthreads();
  float g[4];
  #pragma unroll
  for (int r = 0; r < 4; ++r) {
    int j = t + 256*r;
    const float* w = proj_w + (size_t)j*192;
    float acc = proj_b[j];
    for (int f = 0; f < 192; ++f) acc += feat[f]*w[f];
    g[r] = 0.5f * acc * (1.0f + erff(acc * 0.7071067811865475f));
  }
  int lane = t & 63, wv = t >> 6;
  float s1 = g[0]+g[1]+g[2]+g[3];
  s1 = wave_sum(s1);
  if (lane == 0) red[wv] = s1;
  __syncthreads();
  float mu = (red[0]+red[1]+red[2]+red[3]) * (1.0f/1024.0f);
  __syncthreads();
  float vs = 0.f;
  #pragma unroll
  for (int r = 0; r < 4; ++r) { float d = g[r]-mu; vs += d*d; }
  vs = wave_sum(vs);
  if (lane == 0) red[wv] = vs;
  __syncthreads();
  float var = (red[0]+red[1]+red[2]+red[3]) * (1.0f/1024.0f);
  float is = rsqrtf(var + 1e-5f);
  #pragma unroll
  for (int r = 0; r < 4; ++r) {
    int j = t + 256*r;
    cond[(size_t)b*D_ + j] = (g[r]-mu)*is*ln_g[j] + ln_b[j];
  }
}

// ---------------- embedding sum ----------------------------------------------
__global__ __launch_bounds__(256) void embed_kernel(
    const int* tokens, const float* tok_emb, const float* cond,
    const float* cycle_emb, const float* strength_emb, const int* tcl_p, float* x)
{
  int row = blockIdx.x;
  int b = row >> 10, s = row & 1023;
  int tcl = tcl_p[0];
  int cyc = tcl < MAXCYC_ ? tcl : MAXCYC_;
  int pr  = s % cyc;
  int str = (s % tcl == 0) ? 0 : 3;
  int tok = tokens[row];
  int d = threadIdx.x * 4;
  float4 a = *(const float4*)&tok_emb[(size_t)tok*D_ + d];
  float4 c = *(const float4*)&cond[(size_t)b*D_ + d];
  float4 p = *(const float4*)&cycle_emb[(size_t)pr*D_ + d];
  float4 e = *(const float4*)&strength_emb[(size_t)str*D_ + d];
  float4 o; o.x=a.x+c.x+p.x+e.x; o.y=a.y+c.y+p.y+e.y; o.z=a.z+c.z+p.z+e.z; o.w=a.w+c.w+p.w+e.w;
  *(float4*)&x[(size_t)row*D_ + d] = o;
}

// ---------------- rmsnorm -> bf16 --------------------------------------------
__global__ __launch_bounds__(256) void rmsnorm_kernel(
    const float* x, const float* w, unsigned short* out)
{
  int row = blockIdx.x;
  int t = threadIdx.x;
  __shared__ float red[4];
  const float* xr = x + (size_t)row*D_;
  float4 v = *(const float4*)&xr[t*4];
  float ss = v.x*v.x + v.y*v.y + v.z*v.z + v.w*v.w;
  ss = wave_sum(ss);
  int lane = t & 63, wv = t >> 6;
  if (lane == 0) red[wv] = ss;
  __syncthreads();
  float total = red[0]+red[1]+red[2]+red[3];
  float scale = rsqrtf(total * (1.0f/1024.0f) + 1e-5f);
  float4 wv4 = *(const float4*)&w[t*4];
  ushort4 o;
  o.x = f2bf(wv4.x * v.x * scale);
  o.y = f2bf(wv4.y * v.y * scale);
  o.z = f2bf(wv4.z * v.z * scale);
  o.w = f2bf(wv4.w * v.w * scale);
  *(ushort4*)&out[(size_t)row*D_ + t*4] = o;
}

// ---------------- rope tables -------------------------------------------------
__global__ __launch_bounds__(256) void rope_table_kernel(float* costab, float* sintab)
{
  int i = blockIdx.x*256 + threadIdx.x;
  int s = i >> 6, d = i & 63;
  float inv = powf(10000.0f, -(float)(d & 31) * (1.0f/32.0f));
  float ang = (float)s * inv;
  float sn, cs;
  sincosf(ang, &sn, &cs);
  costab[i] = cs; sintab[i] = sn;
}

// =============== MFMA sliding-window flash attention ==========================
// block = (qtile of 64, h, b); 4 waves, wave w owns queries qb0+w*16..+15.
// q,k,v bf16 (rope applied); y bf16.
__global__ __launch_bounds__(256) void attn_mfma(
    const unsigned short* __restrict__ q, const unsigned short* __restrict__ k,
    const unsigned short* __restrict__ v, unsigned short* __restrict__ y)
{
  __shared__ unsigned short Ks[64*64];     // [key][d], 128B rows, chunk-swizzled
  __shared__ unsigned short VsT[64*72];    // [d][key], ld=72 elems (144B, 16B-aligned)
  __shared__ unsigned short Ps[4*16*72];   // per-wave P / output tile, ld=72

  int qb0 = blockIdx.x * 64;
  int h = blockIdx.y, b = blockIdx.z;
  int t = threadIdx.x, lane = t & 63, wv = t >> 6;
  int c = lane & 15, q4 = lane >> 4;
  unsigned short* Pw = &Ps[wv*16*72];

  // Q A-fragments (row = lane&15, k-slice = q4*8; ksteps 0/1 at k=0/32)
  s16x8 aq[2];
  {
    const unsigned short* qp =
        q + ((size_t)(b*S_ + qb0 + wv*16 + c)*D_ + h*HD_ + q4*8);
    aq[0] = *(const s16x8*)qp;
    aq[1] = *(const s16x8*)(qp + 32);
  }

  f32x4 o[4];
  #pragma unroll
  for (int j = 0; j < 4; ++j) o[j] = (f32x4){0.f,0.f,0.f,0.f};
  float m[4] = {-1e30f,-1e30f,-1e30f,-1e30f};
  float l[4] = {0.f,0.f,0.f,0.f};

  int skey = t >> 2;          // staging: key row 0..63
  int scol = (t & 3) * 16;    // 16 dims per thread
  int kt0 = qb0 - 256; if (kt0 < 0) kt0 = 0;

  for (int kt = kt0; kt <= qb0; kt += 64) {
    __syncthreads();
    // ---- stage K (swizzled) and V^T ----
    {
      const unsigned short* kp = k + ((size_t)(b*S_ + kt + skey)*D_ + h*HD_ + scol);
      s16x8 k0 = *(const s16x8*)kp;
      s16x8 k1 = *(const s16x8*)(kp + 8);
      int ch0 = scol >> 3;   // 0,2,4,6
      *(s16x8*)((char*)Ks + skey*128 + ((ch0 ^ (skey & 7)) << 4)) = k0;
      *(s16x8*)((char*)Ks + skey*128 + (((ch0+1) ^ (skey & 7)) << 4)) = k1;
      const unsigned short* vp = v + ((size_t)(b*S_ + kt + skey)*D_ + h*HD_ + scol);
      s16x8 v0 = *(const s16x8*)vp;
      s16x8 v1 = *(const s16x8*)(vp + 8);
      #pragma unroll
      for (int i = 0; i < 8; ++i) {
        VsT[(scol + i)*72 + skey]     = (unsigned short)v0[i];
        VsT[(scol + 8 + i)*72 + skey] = (unsigned short)v1[i];
      }
    }
    __syncthreads();

    // ---- S = Q * K^T ----
    f32x4 sa[4];
    #pragma unroll
    for (int j = 0; j < 4; ++j) sa[j] = (f32x4){0.f,0.f,0.f,0.f};
    #pragma unroll
    for (int ks = 0; ks < 2; ++ks)
      #pragma unroll
      for (int j = 0; j < 4; ++j) {
        int key = j*16 + c;
        s16x8 bk = *(const s16x8*)((const char*)Ks + key*128 +
                                   (((q4 + ks*4) ^ (key & 7)) << 4));
        sa[j] = __builtin_amdgcn_mfma_f32_16x16x32_bf16(aq[ks], bk, sa[j], 0, 0, 0);
      }

    // ---- mask + online softmax (row = q4*4+reg, col = j*16+c) ----
    float sv[4][4];
    #pragma unroll
    for (int j = 0; j < 4; ++j) {
      int kg = kt + j*16 + c;
      #pragma unroll
      for (int reg = 0; reg < 4; ++reg) {
        int qg = qb0 + wv*16 + q4*4 + reg;
        bool ok = (qg >= kg) && (qg - kg < WIN_);
        sv[j][reg] = ok ? sa[j][reg]*0.125f : -3e38f;
      }
    }
    #pragma unroll
    for (int reg = 0; reg < 4; ++reg) {
      float mx = fmaxf(fmaxf(sv[0][reg], sv[1][reg]), fmaxf(sv[2][reg], sv[3][reg]));
      #pragma unroll
      for (int msk = 1; msk < 16; msk <<= 1)
        mx = fmaxf(mx, __shfl_xor(mx, msk, 64));
      float nm = fmaxf(m[reg], mx);
      float f = __expf(m[reg] - nm);
      m[reg] = nm;
      l[reg] *= f;
      o[0][reg] *= f; o[1][reg] *= f; o[2][reg] *= f; o[3][reg] *= f;
      float ps = 0.f;
      #pragma unroll
      for (int j = 0; j < 4; ++j) {
        float p = __expf(sv[j][reg] - nm);
        ps += p;
        Pw[(q4*4 + reg)*72 + j*16 + c] = f2bf(p);
      }
      l[reg] += ps;
    }

    // ---- O += P * V ----
    #pragma unroll
    for (int ks = 0; ks < 2; ++ks) {
      s16x8 pa = *(const s16x8*)((const char*)Pw + c*144 + (q4 + ks*4)*16);
      #pragma unroll
      for (int j = 0; j < 4; ++j) {
        s16x8 bv = *(const s16x8*)((const char*)VsT + (j*16 + c)*144 + (q4 + ks*4)*16);
        o[j] = __builtin_amdgcn_mfma_f32_16x16x32_bf16(pa, bv, o[j], 0, 0, 0);
      }
    }
  }

  // ---- finalize: reduce l across 16-lane column groups, scale, store ----
  float inv[4];
  #pragma unroll
  for (int reg = 0; reg < 4; ++reg) {
    float ll = l[reg];
    #pragma unroll
    for (int msk = 1; msk < 16; msk <<= 1) ll += __shfl_xor(ll, msk, 64);
    inv[reg] = 1.0f / ll;
  }
  #pragma unroll
  for (int j = 0; j < 4; ++j)
    #pragma unroll
    for (int reg = 0; reg < 4; ++reg)
      Pw[(q4*4 + reg)*72 + j*16 + c] = f2bf(o[j][reg] * inv[reg]);
  // coalesced write-out (per-wave tile, no barrier needed)
  int lr = lane >> 2, cc = (lane & 3)*16;
  s16x8 y0 = *(const s16x8*)((const char*)Pw + lr*144 + cc*2);
  s16x8 y1 = *(const s16x8*)((const char*)Pw + lr*144 + cc*2 + 16);
  unsigned short* yp = y + ((size_t)(b*S_ + qb0 + wv*16 + lr)*D_ + h*HD_ + cc);
  *(s16x8*)yp = y0;
  *(s16x8*)(yp + 8) = y1;
}

// =============== fused W1/W3 GEMM: 128x128 tile, dual accumulator =============
__global__ __launch_bounds__(256, 2) void gemm_w13(
    const unsigned short* __restrict__ A,
    const unsigned short* __restrict__ W1, const unsigned short* __restrict__ W3,
    unsigned short* __restrict__ T, int K, int lda, int ldw)
{
  __shared__ unsigned short sA[2][128*32];
  __shared__ unsigned short sW1[2][128*32];
  __shared__ unsigned short sW3[2][128*32];
  int tid = threadIdx.x, lane = tid & 63, wave = tid >> 6;
  int wr = (wave >> 1)*64, wc = (wave & 1)*64;
  size_t bm = (size_t)blockIdx.x*128, bn = (size_t)blockIdx.y*128;
  int fr = lane & 15, fk = (lane >> 4)*8, fq = (lane >> 4)*4;
  int rseg = lane >> 2, chunk = (lane & 3)*8;

  f32x4 a1[4][4], a3[4][4];
  #pragma unroll
  for (int i = 0; i < 4; ++i)
    #pragma unroll
    for (int j = 0; j < 4; ++j) {
      a1[i][j] = (f32x4){0.f,0.f,0.f,0.f};
      a3[i][j] = (f32x4){0.f,0.f,0.f,0.f};
    }

  auto stage = [&](int buf, int kt) {
    #pragma unroll
    for (int p = 0; p < 2; ++p) {
      int seg = wave*2 + p;
      int row = seg*16 + rseg;
      gload16(A  + (bm + row)*(size_t)lda + kt + chunk, &sA[buf][seg*512]);
      gload16(W1 + (bn + row)*(size_t)ldw + kt + chunk, &sW1[buf][seg*512]);
      gload16(W3 + (bn + row)*(size_t)ldw + kt + chunk, &sW3[buf][seg*512]);
    }
  };

  stage(0, 0);
  __syncthreads();
  int nt = K >> 5;
  for (int t = 0; t < nt; ++t) {
    int cur = t & 1;
    if (t + 1 < nt) stage(cur ^ 1, (t+1)*32);
    s16x8 af[4], b1[4], b3[4];
    #pragma unroll
    for (int i = 0; i < 4; ++i) {
      af[i] = *(const s16x8*)&sA[cur][(wr + i*16 + fr)*32 + fk];
      b1[i] = *(const s16x8*)&sW1[cur][(wc + i*16 + fr)*32 + fk];
      b3[i] = *(const s16x8*)&sW3[cur][(wc + i*16 + fr)*32 + fk];
    }
    #pragma unroll
    for (int i = 0; i < 4; ++i)
      #pragma unroll
      for (int j = 0; j < 4; ++j) {
        a1[i][j] = __builtin_amdgcn_mfma_f32_16x16x32_bf16(af[i], b1[j], a1[i][j], 0, 0, 0);
        a3[i][j] = __builtin_amdgcn_mfma_f32_16x16x32_bf16(af[i], b3[j], a3[i][j], 0, 0, 0);
      }
    __syncthreads();
  }

  #pragma unroll
  for (int i = 0; i < 4; ++i)
    #pragma unroll
    for (int j = 0; j < 4; ++j) {
      size_t row0 = bm + wr + i*16 + fq;
      size_t col  = bn + wc + j*16 + fr;
      #pragma unroll
      for (int qi = 0; qi < 4; ++qi) {
        float u = a1[i][j][qi];
        float g = a3[i][j][qi];
        float su = u / (1.0f + __expf(-u));
        T[(row0 + qi)*(size_t)FF_ + col] = f2bf(su * g);
      }
    }
}

// =============== generic GEMM: 128x64 tile ====================================
// EPI: 0 = store f32, 1 = add f32, 3 = rope->bf16, 4 = bf16
template<int EPI>
__device__ __forceinline__ void gemm64_core(
    const unsigned short* __restrict__ A, const unsigned short* __restrict__ W,
    float* __restrict__ Cf, unsigned short* __restrict__ Cb,
    int K, int lda, int ldw, int ldc,
    const float* __restrict__ costab, const float* __restrict__ sintab)
{
  __shared__ unsigned short sA[2][128*32];
  __shared__ unsigned short sW[2][64*32];
  int tid = threadIdx.x, lane = tid & 63, wave = tid >> 6;
  int wr = (wave >> 1)*64, wc = (wave & 1)*32;
  size_t bm = (size_t)blockIdx.x*128, bn = (size_t)blockIdx.y*64;
  int fr = lane & 15, fk = (lane >> 4)*8, fq = (lane >> 4)*4;
  int rseg = lane >> 2, chunk = (lane & 3)*8;

  f32x4 acc[4][2];
  #pragma unroll
  for (int i = 0; i < 4; ++i) {
    acc[i][0] = (f32x4){0.f,0.f,0.f,0.f};
    acc[i][1] = (f32x4){0.f,0.f,0.f,0.f};
  }

  auto stage = [&](int buf, int kt) {
    #pragma unroll
    for (int p = 0; p < 2; ++p) {
      int seg = wave*2 + p;
      int row = seg*16 + rseg;
      gload16(A + (bm + row)*(size_t)lda + kt + chunk, &sA[buf][seg*512]);
    }
    int row = wave*16 + rseg;
    gload16(W + (bn + row)*(size_t)ldw + kt + chunk, &sW[buf][wave*512]);
  };

  stage(0, 0);
  __syncthreads();
  int nt = K >> 5;
  for (int t = 0; t < nt; ++t) {
    int cur = t & 1;
    if (t + 1 < nt) stage(cur ^ 1, (t+1)*32);
    s16x8 af[4], bw[2];
    #pragma unroll
    for (int i = 0; i < 4; ++i)
      af[i] = *(const s16x8*)&sA[cur][(wr + i*16 + fr)*32 + fk];
    #pragma unroll
    for (int j = 0; j < 2; ++j)
      bw[j] = *(const s16x8*)&sW[cur][(wc + j*16 + fr)*32 + fk];
    #pragma unroll
    for (int i = 0; i < 4; ++i)
      #pragma unroll
      for (int j = 0; j < 2; ++j)
        acc[i][j] = __builtin_amdgcn_mfma_f32_16x16x32_bf16(af[i], bw[j], acc[i][j], 0, 0, 0);
    __syncthreads();
  }

  #pragma unroll
  for (int i = 0; i < 4; ++i)
    #pragma unroll
    for (int j = 0; j < 2; ++j) {
      size_t row0 = bm + wr + i*16 + fq;
      size_t col  = bn + wc + j*16 + fr;
      #pragma unroll
      for (int qi = 0; qi < 4; ++qi) {
        float val = acc[i][j][qi];
        size_t idx = (row0 + qi)*(size_t)ldc + col;
        if (EPI == 3) {
          float pv = __shfl_xor(val, 1, 64);
          int srow = (int)((row0 + qi) & 1023);
          int d = (int)(col & 63);
          float cs = costab[srow*64 + d];
          float sn = sintab[srow*64 + d];
          Cb[idx] = f2bf(val*cs + ((d & 1) ? pv : -pv)*sn);
        } else if (EPI == 4) {
          Cb[idx] = f2bf(val);
        } else if (EPI == 1) {
          Cf[idx] += val;
        } else {
          Cf[idx] = val;
        }
      }
    }
}

template<int EPI>
__global__ __launch_bounds__(256) void gemm64(
    const unsigned short* __restrict__ A, const unsigned short* __restrict__ W,
    float* __restrict__ Cf, int K, int lda, int ldw, int ldc)
{
  gemm64_core<EPI>(A, W, Cf, nullptr, K, lda, ldw, ldc, nullptr, nullptr);
}

__global__ __launch_bounds__(256) void gemm_qkv64(
    const unsigned short* __restrict__ A,
    const unsigned short* __restrict__ Wq, const unsigned short* __restrict__ Wk,
    const unsigned short* __restrict__ Wv,
    unsigned short* __restrict__ Cq, unsigned short* __restrict__ Ck,
    unsigned short* __restrict__ Cv,
    const float* __restrict__ costab, const float* __restrict__ sintab)
{
  if (blockIdx.z == 0)
    gemm64_core<3>(A, Wq, nullptr, Cq, D_, D_, D_, D_, costab, sintab);
  else if (blockIdx.z == 1)
    gemm64_core<3>(A, Wk, nullptr, Ck, D_, D_, D_, D_, costab, sintab);
  else
    gemm64_core<4>(A, Wv, nullptr, Cv, D_, D_, D_, D_, nullptr, nullptr);
}

// ---------------- host launcher -----------------------------------------------
extern "C" void kernel_launch(void* const* d_in, const int* in_sizes, int n_in,
                              void* d_out, int out_size, void* d_ws, size_t ws_size,
                              hipStream_t stream)
{
  const int*   tokens    = (const int*)d_in[0];
  const int*   mood      = (const int*)d_in[1];
  const int*   raga      = (const int*)d_in[2];
  const int*   taal      = (const int*)d_in[3];
  const float* tempo     = (const float*)d_in[4];
  const float* duration  = (const float*)d_in[5];
  const int*   tcl       = (const int*)d_in[6];
  const float* tok_emb   = (const float*)d_in[7];
  const float* mood_emb  = (const float*)d_in[8];
  const float* raga_emb  = (const float*)d_in[9];
  const float* taal_emb  = (const float*)d_in[10];
  const float* tempo_w   = (const float*)d_in[11];
  const float* tempo_b   = (const float*)d_in[12];
  const float* dur_w     = (const float*)d_in[13];
  const float* dur_b     = (const float*)d_in[14];
  const float* proj_w    = (const float*)d_in[15];
  const float* proj_b    = (const float*)d_in[16];
  const float* ln_g      = (const float*)d_in[17];
  const float* ln_b      = (const float*)d_in[18];
  const float* cycle_emb = (const float*)d_in[19];
  const float* strength_e= (const float*)d_in[20];
  const float* l_anorm   = (const float*)d_in[21];
  const float* l_fnorm   = (const float*)d_in[22];
  const float* l_q       = (const float*)d_in[23];
  const float* l_k       = (const float*)d_in[24];
  const float* l_v       = (const float*)d_in[25];
  const float* l_o       = (const float*)d_in[26];
  const float* l_w1      = (const float*)d_in[27];
  const float* l_w2      = (const float*)d_in[28];
  const float* l_w3      = (const float*)d_in[29];
  const float* final_norm= (const float*)d_in[30];
  const float* head_w    = (const float*)d_in[31];

  size_t off = 0;
  char* wsb = (char*)d_ws;
  auto alloc = [&](size_t bytes) -> char* {
    char* p = wsb + off;
    off += (bytes + 255) & ~(size_t)255;
    return p;
  };
  float*          condb  = (float*)alloc((size_t)B_*D_*4);
  float*          costab = (float*)alloc((size_t)S_*HD_*4);
  float*          sintab = (float*)alloc((size_t)S_*HD_*4);
  float*          x      = (float*)alloc((size_t)B_*S_*D_*4);
  unsigned short* hbuf   = (unsigned short*)alloc((size_t)B_*S_*D_*2);
  unsigned short* qb     = (unsigned short*)alloc((size_t)B_*S_*D_*2);
  unsigned short* kb     = (unsigned short*)alloc((size_t)B_*S_*D_*2);
  unsigned short* vb     = (unsigned short*)alloc((size_t)B_*S_*D_*2);
  unsigned short* yb     = (unsigned short*)alloc((size_t)B_*S_*D_*2);
  unsigned short* tb     = (unsigned short*)alloc((size_t)B_*S_*FF_*2);

  const size_t N_QKVO = (size_t)L_*D_*D_;
  const size_t N_FF   = (size_t)L_*FF_*D_;
  const size_t N_HEAD = (size_t)V_*D_;
  unsigned short* wbf = (unsigned short*)alloc((4*N_QKVO + 3*N_FF + N_HEAD)*2);
  unsigned short* bq = wbf;
  unsigned short* bk = wbf + N_QKVO;
  unsigned short* bv = wbf + 2*N_QKVO;
  unsigned short* bo = wbf + 3*N_QKVO;
  unsigned short* b1 = wbf + 4*N_QKVO;
  unsigned short* b2 = wbf + 4*N_QKVO + N_FF;
  unsigned short* b3 = wbf + 4*N_QKVO + 2*N_FF;
  unsigned short* bh = wbf + 4*N_QKVO + 3*N_FF;

  rope_table_kernel<<<(S_*HD_)/256, 256, 0, stream>>>(costab, sintab);
  cond_kernel<<<B_, 256, 0, stream>>>(mood, raga, taal, tempo, duration,
      mood_emb, raga_emb, taal_emb, tempo_w, tempo_b, dur_w, dur_b,
      proj_w, proj_b, ln_g, ln_b, condb);
  embed_kernel<<<B_*S_, 256, 0, stream>>>(tokens, tok_emb, condb, cycle_emb,
      strength_e, tcl, x);

  cvt_kernel<<<(int)(N_QKVO/8/256), 256, 0, stream>>>(l_q,  bq, (int)(N_QKVO/8));
  cvt_kernel<<<(int)(N_QKVO/8/256), 256, 0, stream>>>(l_k,  bk, (int)(N_QKVO/8));
  cvt_kernel<<<(int)(N_QKVO/8/256), 256, 0, stream>>>(l_v,  bv, (int)(N_QKVO/8));
  cvt_kernel<<<(int)(N_QKVO/8/256), 256, 0, stream>>>(l_o,  bo, (int)(N_QKVO/8));
  cvt_kernel<<<(int)(N_FF/8/256),   256, 0, stream>>>(l_w1, b1, (int)(N_FF/8));
  cvt_kernel<<<(int)(N_FF/8/256),   256, 0, stream>>>(l_w2, b2, (int)(N_FF/8));
  cvt_kernel<<<(int)(N_FF/8/256),   256, 0, stream>>>(l_w3, b3, (int)(N_FF/8));
  cvt_kernel<<<(int)(N_HEAD/8/256), 256, 0, stream>>>(head_w, bh, (int)(N_HEAD/8));

  const int rows = B_*S_;   // 2048
  for (int l = 0; l < L_; ++l) {
    size_t dd = (size_t)l*D_*D_;
    size_t fd = (size_t)l*FF_*D_;
    rmsnorm_kernel<<<rows, 256, 0, stream>>>(x, l_anorm + (size_t)l*D_, hbuf);
    gemm_qkv64<<<dim3(rows/128, D_/64, 3), 256, 0, stream>>>(
        hbuf, bq + dd, bk + dd, bv + dd, qb, kb, vb, costab, sintab);
    attn_mfma<<<dim3(S_/64, H_, B_), 256, 0, stream>>>(qb, kb, vb, yb);
    gemm64<1><<<dim3(rows/128, D_/64), 256, 0, stream>>>(
        yb, bo + dd, x, D_, D_, D_, D_);
    rmsnorm_kernel<<<rows, 256, 0, stream>>>(x, l_fnorm + (size_t)l*D_, hbuf);
    gemm_w13<<<dim3(rows/128, FF_/128), 256, 0, stream>>>(
        hbuf, b1 + fd, b3 + fd, tb, D_, D_, D_);
    gemm64<1><<<dim3(rows/128, D_/64), 256, 0, stream>>>(
        tb, b2 + fd, x, FF_, FF_, FF_, D_);
  }
  rmsnorm_kernel<<<rows, 256, 0, stream>>>(x, final_norm, hbuf);
  gemm64<0><<<dim3(rows/128, V_/64), 256, 0, stream>>>(
      hbuf, bh, (float*)d_out, D_, D_, D_, V_);
}

// Round 5
// 1781.601 us; speedup vs baseline: 2.9580x; 1.0652x over previous
//
#include <hip/hip_runtime.h>
#include <math.h>

#define D_ 1024
#define H_ 16
#define HD_ 64
#define L_ 8
#define V_ 2048
#define FF_ 4096
#define WIN_ 256
#define B_ 2
#define S_ 1024
#define MAXCYC_ 16

typedef __attribute__((ext_vector_type(4))) float f32x4;
typedef __attribute__((ext_vector_type(8))) short s16x8;

__device__ __forceinline__ unsigned short f2bf(float f) {
  union { float f; unsigned int u; } v; v.f = f;
  unsigned int r = v.u + 0x7FFFu + ((v.u >> 16) & 1u);
  return (unsigned short)(r >> 16);
}

__device__ __forceinline__ float wave_sum(float v) {
  #pragma unroll
  for (int m = 1; m < 64; m <<= 1) v += __shfl_xor(v, m, 64);
  return v;
}

// async global->LDS, 16B per lane. dst wave-uniform base; HW writes dst+lane*16.
__device__ __forceinline__ void gload16(const unsigned short* g, unsigned short* lds) {
  __builtin_amdgcn_global_load_lds(
      (const __attribute__((address_space(1))) void*)g,
      (__attribute__((address_space(3))) void*)lds,
      16, 0, 0);
}

// ---------------- f32 -> bf16 convert (weights) ------------------------------
__global__ __launch_bounds__(256) void cvt_kernel(
    const float* __restrict__ src, unsigned short* __restrict__ dst, int n8)
{
  int i = blockIdx.x*256 + threadIdx.x;
  if (i >= n8) return;
  const float4* s = (const float4*)src + (size_t)i*2;
  float4 a = s[0], b = s[1];
  ushort4 lo, hi;
  lo.x = f2bf(a.x); lo.y = f2bf(a.y); lo.z = f2bf(a.z); lo.w = f2bf(a.w);
  hi.x = f2bf(b.x); hi.y = f2bf(b.y); hi.z = f2bf(b.z); hi.w = f2bf(b.w);
  *(ushort4*)(dst + (size_t)i*8)     = lo;
  *(ushort4*)(dst + (size_t)i*8 + 4) = hi;
}

// ---------------- conditioning ----------------------------------------------
__global__ __launch_bounds__(256) void cond_kernel(
    const int* mood, const int* raga, const int* taal,
    const float* tempo, const float* duration,
    const float* mood_emb, const float* raga_emb, const float* taal_emb,
    const float* tempo_w, const float* tempo_b, const float* dur_w, const float* dur_b,
    const float* proj_w, const float* proj_b, const float* ln_g, const float* ln_b,
    float* cond)
{
  int b = blockIdx.x;
  int t = threadIdx.x;
  __shared__ float feat[192];
  __shared__ float red[4];
  if (t < 64)        feat[t] = mood_emb[mood[b]*64 + t];
  else if (t < 128)  feat[t] = raga_emb[raga[b]*64 + (t-64)];
  else if (t < 160)  feat[t] = taal_emb[taal[b]*32 + (t-128)];
  else if (t < 176)  feat[t] = tempo[b]*tempo_w[t-160] + tempo_b[t-160];
  else if (t < 192)  feat[t] = duration[b]*dur_w[t-176] + dur_b[t-176];
  __syncthreads();
  float g[4];
  #pragma unroll
  for (int r = 0; r < 4; ++r) {
    int j = t + 256*r;
    const float* w = proj_w + (size_t)j*192;
    float acc = proj_b[j];
    for (int f = 0; f < 192; ++f) acc += feat[f]*w[f];
    g[r] = 0.5f * acc * (1.0f + erff(acc * 0.7071067811865475f));
  }
  int lane = t & 63, wv = t >> 6;
  float s1 = g[0]+g[1]+g[2]+g[3];
  s1 = wave_sum(s1);
  if (lane == 0) red[wv] = s1;
  __syncthreads();
  float mu = (red[0]+red[1]+red[2]+red[3]) * (1.0f/1024.0f);
  __syncthreads();
  float vs = 0.f;
  #pragma unroll
  for (int r = 0; r < 4; ++r) { float d = g[r]-mu; vs += d*d; }
  vs = wave_sum(vs);
  if (lane == 0) red[wv] = vs;
  __syncthreads();
  float var = (red[0]+red[1]+red[2]+red[3]) * (1.0f/1024.0f);
  float is = rsqrtf(var + 1e-5f);
  #pragma unroll
  for (int r = 0; r < 4; ++r) {
    int j = t + 256*r;
    cond[(size_t)b*D_ + j] = (g[r]-mu)*is*ln_g[j] + ln_b[j];
  }
}

// ---------------- embedding sum ----------------------------------------------
__global__ __launch_bounds__(256) void embed_kernel(
    const int* tokens, const float* tok_emb, const float* cond,
    const float* cycle_emb, const float* strength_emb, const int* tcl_p, float* x)
{
  int row = blockIdx.x;
  int b = row >> 10, s = row & 1023;
  int tcl = tcl_p[0];
  int cyc = tcl < MAXCYC_ ? tcl : MAXCYC_;
  int pr  = s % cyc;
  int str = (s % tcl == 0) ? 0 : 3;
  int tok = tokens[row];
  int d = threadIdx.x * 4;
  float4 a = *(const float4*)&tok_emb[(size_t)tok*D_ + d];
  float4 c = *(const float4*)&cond[(size_t)b*D_ + d];
  float4 p = *(const float4*)&cycle_emb[(size_t)pr*D_ + d];
  float4 e = *(const float4*)&strength_emb[(size_t)str*D_ + d];
  float4 o; o.x=a.x+c.x+p.x+e.x; o.y=a.y+c.y+p.y+e.y; o.z=a.z+c.z+p.z+e.z; o.w=a.w+c.w+p.w+e.w;
  *(float4*)&x[(size_t)row*D_ + d] = o;
}

// ---------------- rmsnorm -> bf16 --------------------------------------------
__global__ __launch_bounds__(256) void rmsnorm_kernel(
    const float* x, const float* w, unsigned short* out)
{
  int row = blockIdx.x;
  int t = threadIdx.x;
  __shared__ float red[4];
  const float* xr = x + (size_t)row*D_;
  float4 v = *(const float4*)&xr[t*4];
  float ss = v.x*v.x + v.y*v.y + v.z*v.z + v.w*v.w;
  ss = wave_sum(ss);
  int lane = t & 63, wv = t >> 6;
  if (lane == 0) red[wv] = ss;
  __syncthreads();
  float total = red[0]+red[1]+red[2]+red[3];
  float scale = rsqrtf(total * (1.0f/1024.0f) + 1e-5f);
  float4 wv4 = *(const float4*)&w[t*4];
  ushort4 o;
  o.x = f2bf(wv4.x * v.x * scale);
  o.y = f2bf(wv4.y * v.y * scale);
  o.z = f2bf(wv4.z * v.z * scale);
  o.w = f2bf(wv4.w * v.w * scale);
  *(ushort4*)&out[(size_t)row*D_ + t*4] = o;
}

// -------- fused: x += sum(partials); rmsnorm(x) -> bf16 -----------------------
__global__ __launch_bounds__(256) void resid_rmsnorm_kernel(
    float* __restrict__ x, const float* __restrict__ part, int nparts,
    const float* __restrict__ w, unsigned short* __restrict__ out)
{
  int row = blockIdx.x;
  int t = threadIdx.x;
  __shared__ float red[4];
  size_t base = (size_t)row*D_ + t*4;
  const size_t pstride = (size_t)B_*S_*D_;
  float4 v = *(const float4*)&x[base];
  for (int p = 0; p < nparts; ++p) {
    float4 a = *(const float4*)&part[p*pstride + base];
    v.x += a.x; v.y += a.y; v.z += a.z; v.w += a.w;
  }
  *(float4*)&x[base] = v;
  float ss = v.x*v.x + v.y*v.y + v.z*v.z + v.w*v.w;
  ss = wave_sum(ss);
  int lane = t & 63, wv = t >> 6;
  if (lane == 0) red[wv] = ss;
  __syncthreads();
  float total = red[0]+red[1]+red[2]+red[3];
  float scale = rsqrtf(total * (1.0f/1024.0f) + 1e-5f);
  float4 wv4 = *(const float4*)&w[t*4];
  ushort4 o;
  o.x = f2bf(wv4.x * v.x * scale);
  o.y = f2bf(wv4.y * v.y * scale);
  o.z = f2bf(wv4.z * v.z * scale);
  o.w = f2bf(wv4.w * v.w * scale);
  *(ushort4*)&out[(size_t)row*D_ + t*4] = o;
}

// ---------------- rope tables -------------------------------------------------
__global__ __launch_bounds__(256) void rope_table_kernel(float* costab, float* sintab)
{
  int i = blockIdx.x*256 + threadIdx.x;
  int s = i >> 6, d = i & 63;
  float inv = powf(10000.0f, -(float)(d & 31) * (1.0f/32.0f));
  float ang = (float)s * inv;
  float sn, cs;
  sincosf(ang, &sn, &cs);
  costab[i] = cs; sintab[i] = sn;
}

// =============== MFMA sliding-window flash attention ==========================
__global__ __launch_bounds__(256) void attn_mfma(
    const unsigned short* __restrict__ q, const unsigned short* __restrict__ k,
    const unsigned short* __restrict__ v, unsigned short* __restrict__ y)
{
  __shared__ unsigned short Ks[64*64];     // [key][d], 128B rows, chunk-swizzled
  __shared__ unsigned short VsT[64*72];    // [d][key], ld=72
  __shared__ unsigned short Ps[4*16*72];   // per-wave P / output tile

  int qb0 = blockIdx.x * 64;
  int h = blockIdx.y, b = blockIdx.z;
  int t = threadIdx.x, lane = t & 63, wv = t >> 6;
  int c = lane & 15, q4 = lane >> 4;
  unsigned short* Pw = &Ps[wv*16*72];

  s16x8 aq[2];
  {
    const unsigned short* qp =
        q + ((size_t)(b*S_ + qb0 + wv*16 + c)*D_ + h*HD_ + q4*8);
    aq[0] = *(const s16x8*)qp;
    aq[1] = *(const s16x8*)(qp + 32);
  }

  f32x4 o[4];
  #pragma unroll
  for (int j = 0; j < 4; ++j) o[j] = (f32x4){0.f,0.f,0.f,0.f};
  float m[4] = {-1e30f,-1e30f,-1e30f,-1e30f};
  float l[4] = {0.f,0.f,0.f,0.f};

  int skey = t >> 2;
  int scol = (t & 3) * 16;
  int kt0 = qb0 - 256; if (kt0 < 0) kt0 = 0;

  for (int kt = kt0; kt <= qb0; kt += 64) {
    __syncthreads();
    {
      const unsigned short* kp = k + ((size_t)(b*S_ + kt + skey)*D_ + h*HD_ + scol);
      s16x8 k0 = *(const s16x8*)kp;
      s16x8 k1 = *(const s16x8*)(kp + 8);
      int ch0 = scol >> 3;
      *(s16x8*)((char*)Ks + skey*128 + ((ch0 ^ (skey & 7)) << 4)) = k0;
      *(s16x8*)((char*)Ks + skey*128 + (((ch0+1) ^ (skey & 7)) << 4)) = k1;
      const unsigned short* vp = v + ((size_t)(b*S_ + kt + skey)*D_ + h*HD_ + scol);
      s16x8 v0 = *(const s16x8*)vp;
      s16x8 v1 = *(const s16x8*)(vp + 8);
      #pragma unroll
      for (int i = 0; i < 8; ++i) {
        VsT[(scol + i)*72 + skey]     = (unsigned short)v0[i];
        VsT[(scol + 8 + i)*72 + skey] = (unsigned short)v1[i];
      }
    }
    __syncthreads();

    f32x4 sa[4];
    #pragma unroll
    for (int j = 0; j < 4; ++j) sa[j] = (f32x4){0.f,0.f,0.f,0.f};
    #pragma unroll
    for (int ks = 0; ks < 2; ++ks)
      #pragma unroll
      for (int j = 0; j < 4; ++j) {
        int key = j*16 + c;
        s16x8 bk = *(const s16x8*)((const char*)Ks + key*128 +
                                   (((q4 + ks*4) ^ (key & 7)) << 4));
        sa[j] = __builtin_amdgcn_mfma_f32_16x16x32_bf16(aq[ks], bk, sa[j], 0, 0, 0);
      }

    float sv[4][4];
    #pragma unroll
    for (int j = 0; j < 4; ++j) {
      int kg = kt + j*16 + c;
      #pragma unroll
      for (int reg = 0; reg < 4; ++reg) {
        int qg = qb0 + wv*16 + q4*4 + reg;
        bool ok = (qg >= kg) && (qg - kg < WIN_);
        sv[j][reg] = ok ? sa[j][reg]*0.125f : -3e38f;
      }
    }
    #pragma unroll
    for (int reg = 0; reg < 4; ++reg) {
      float mx = fmaxf(fmaxf(sv[0][reg], sv[1][reg]), fmaxf(sv[2][reg], sv[3][reg]));
      #pragma unroll
      for (int msk = 1; msk < 16; msk <<= 1)
        mx = fmaxf(mx, __shfl_xor(mx, msk, 64));
      float nm = fmaxf(m[reg], mx);
      float f = __expf(m[reg] - nm);
      m[reg] = nm;
      l[reg] *= f;
      o[0][reg] *= f; o[1][reg] *= f; o[2][reg] *= f; o[3][reg] *= f;
      float ps = 0.f;
      #pragma unroll
      for (int j = 0; j < 4; ++j) {
        float p = __expf(sv[j][reg] - nm);
        ps += p;
        Pw[(q4*4 + reg)*72 + j*16 + c] = f2bf(p);
      }
      l[reg] += ps;
    }

    #pragma unroll
    for (int ks = 0; ks < 2; ++ks) {
      s16x8 pa = *(const s16x8*)((const char*)Pw + c*144 + (q4 + ks*4)*16);
      #pragma unroll
      for (int j = 0; j < 4; ++j) {
        s16x8 bv = *(const s16x8*)((const char*)VsT + (j*16 + c)*144 + (q4 + ks*4)*16);
        o[j] = __builtin_amdgcn_mfma_f32_16x16x32_bf16(pa, bv, o[j], 0, 0, 0);
      }
    }
  }

  float inv[4];
  #pragma unroll
  for (int reg = 0; reg < 4; ++reg) {
    float ll = l[reg];
    #pragma unroll
    for (int msk = 1; msk < 16; msk <<= 1) ll += __shfl_xor(ll, msk, 64);
    inv[reg] = 1.0f / ll;
  }
  #pragma unroll
  for (int j = 0; j < 4; ++j)
    #pragma unroll
    for (int reg = 0; reg < 4; ++reg)
      Pw[(q4*4 + reg)*72 + j*16 + c] = f2bf(o[j][reg] * inv[reg]);
  int lr = lane >> 2, cc = (lane & 3)*16;
  s16x8 y0 = *(const s16x8*)((const char*)Pw + lr*144 + cc*2);
  s16x8 y1 = *(const s16x8*)((const char*)Pw + lr*144 + cc*2 + 16);
  unsigned short* yp = y + ((size_t)(b*S_ + qb0 + wv*16 + lr)*D_ + h*HD_ + cc);
  *(s16x8*)yp = y0;
  *(s16x8*)(yp + 8) = y1;
}

// =============== fused W1/W3 GEMM: 128x128 tile, BK=32, swizzled ==============
__global__ __launch_bounds__(256, 2) void gemm_w13(
    const unsigned short* __restrict__ A,
    const unsigned short* __restrict__ W1, const unsigned short* __restrict__ W3,
    unsigned short* __restrict__ T, int K, int lda, int ldw)
{
  __shared__ unsigned short sA[2][128*32];
  __shared__ unsigned short sW1[2][128*32];
  __shared__ unsigned short sW3[2][128*32];
  int tid = threadIdx.x, lane = tid & 63, wave = tid >> 6;
  int wr = (wave >> 1)*64, wc = (wave & 1)*64;
  size_t bm = (size_t)blockIdx.x*128, bn = (size_t)blockIdx.y*128;
  int fr = lane & 15, q4 = lane >> 4, fq = q4*4;
  int lrow = lane >> 2;                       // row within 16-row seg
  int gcol = ((lane & 3) ^ (lrow & 3)) * 8;   // pre-swizzled global chunk

  f32x4 a1[4][4], a3[4][4];
  #pragma unroll
  for (int i = 0; i < 4; ++i)
    #pragma unroll
    for (int j = 0; j < 4; ++j) {
      a1[i][j] = (f32x4){0.f,0.f,0.f,0.f};
      a3[i][j] = (f32x4){0.f,0.f,0.f,0.f};
    }

  auto stage = [&](int buf, int kt) {
    #pragma unroll
    for (int p = 0; p < 2; ++p) {
      int seg = wave*2 + p;
      size_t row = (size_t)(seg*16 + lrow);
      gload16(A  + (bm + row)*(size_t)lda + kt + gcol, &sA[buf][seg*512]);
      gload16(W1 + (bn + row)*(size_t)ldw + kt + gcol, &sW1[buf][seg*512]);
      gload16(W3 + (bn + row)*(size_t)ldw + kt + gcol, &sW3[buf][seg*512]);
    }
  };

  stage(0, 0);
  __syncthreads();
  int nt = K >> 5;
  for (int t = 0; t < nt; ++t) {
    int cur = t & 1;
    if (t + 1 < nt) stage(cur ^ 1, (t+1)*32);
    s16x8 af[4], b1[4], b3[4];
    #pragma unroll
    for (int i = 0; i < 4; ++i) {
      int ra = wr + i*16 + fr, rb = wc + i*16 + fr;
      af[i] = *(const s16x8*)((const char*)&sA[cur][0]  + ra*64 + ((q4 ^ (ra & 3)) << 4));
      b1[i] = *(const s16x8*)((const char*)&sW1[cur][0] + rb*64 + ((q4 ^ (rb & 3)) << 4));
      b3[i] = *(const s16x8*)((const char*)&sW3[cur][0] + rb*64 + ((q4 ^ (rb & 3)) << 4));
    }
    #pragma unroll
    for (int i = 0; i < 4; ++i)
      #pragma unroll
      for (int j = 0; j < 4; ++j) {
        a1[i][j] = __builtin_amdgcn_mfma_f32_16x16x32_bf16(af[i], b1[j], a1[i][j], 0, 0, 0);
        a3[i][j] = __builtin_amdgcn_mfma_f32_16x16x32_bf16(af[i], b3[j], a3[i][j], 0, 0, 0);
      }
    __syncthreads();
  }

  #pragma unroll
  for (int i = 0; i < 4; ++i)
    #pragma unroll
    for (int j = 0; j < 4; ++j) {
      size_t row0 = bm + wr + i*16 + fq;
      size_t col  = bn + wc + j*16 + fr;
      #pragma unroll
      for (int qi = 0; qi < 4; ++qi) {
        float u = a1[i][j][qi];
        float g = a3[i][j][qi];
        float su = u / (1.0f + __expf(-u));
        T[(row0 + qi)*(size_t)FF_ + col] = f2bf(su * g);
      }
    }
}

// =============== generic GEMM: 128x64 tile, BK=64, swizzled ===================
// EPI: 0 = store f32, 3 = rope->bf16, 4 = bf16
template<int EPI>
__device__ __forceinline__ void gemm64_core(
    const unsigned short* __restrict__ A, const unsigned short* __restrict__ W,
    float* __restrict__ Cf, unsigned short* __restrict__ Cb,
    int kbase, int Kslice, int lda, int ldw, int ldc,
    const float* __restrict__ costab, const float* __restrict__ sintab)
{
  __shared__ unsigned short sA[2][128*64];
  __shared__ unsigned short sW[2][64*64];
  int tid = threadIdx.x, lane = tid & 63, wave = tid >> 6;
  int wr = (wave >> 1)*64, wc = (wave & 1)*32;
  size_t bm = (size_t)blockIdx.x*128, bn = (size_t)blockIdx.y*64;
  int fr = lane & 15, q4 = lane >> 4, fq = q4*4;
  int lrow = lane >> 3;                   // row within 8-row seg
  int gcol = ((lane & 7) ^ lrow) * 8;     // pre-swizzled global chunk

  f32x4 acc[4][2];
  #pragma unroll
  for (int i = 0; i < 4; ++i) {
    acc[i][0] = (f32x4){0.f,0.f,0.f,0.f};
    acc[i][1] = (f32x4){0.f,0.f,0.f,0.f};
  }

  auto stage = [&](int buf, int kt) {
    #pragma unroll
    for (int p = 0; p < 4; ++p) {
      int seg = wave*4 + p;
      gload16(A + (bm + seg*8 + lrow)*(size_t)lda + kt + gcol, &sA[buf][seg*512]);
    }
    #pragma unroll
    for (int p = 0; p < 2; ++p) {
      int seg = wave*2 + p;
      gload16(W + (bn + seg*8 + lrow)*(size_t)ldw + kt + gcol, &sW[buf][seg*512]);
    }
  };

  stage(0, kbase);
  __syncthreads();
  int nt = Kslice >> 6;
  for (int t = 0; t < nt; ++t) {
    int cur = t & 1;
    if (t + 1 < nt) stage(cur ^ 1, kbase + (t+1)*64);
    #pragma unroll
    for (int ks = 0; ks < 2; ++ks) {
      s16x8 af[4], bw[2];
      #pragma unroll
      for (int i = 0; i < 4; ++i) {
        int r = wr + i*16 + fr;
        af[i] = *(const s16x8*)((const char*)&sA[cur][0] + r*128 +
                                ((((ks<<2) + q4) ^ (r & 7)) << 4));
      }
      #pragma unroll
      for (int j = 0; j < 2; ++j) {
        int r = wc + j*16 + fr;
        bw[j] = *(const s16x8*)((const char*)&sW[cur][0] + r*128 +
                                ((((ks<<2) + q4) ^ (r & 7)) << 4));
      }
      #pragma unroll
      for (int i = 0; i < 4; ++i)
        #pragma unroll
        for (int j = 0; j < 2; ++j)
          acc[i][j] = __builtin_amdgcn_mfma_f32_16x16x32_bf16(af[i], bw[j], acc[i][j], 0, 0, 0);
    }
    __syncthreads();
  }

  #pragma unroll
  for (int i = 0; i < 4; ++i)
    #pragma unroll
    for (int j = 0; j < 2; ++j) {
      size_t row0 = bm + wr + i*16 + fq;
      size_t col  = bn + wc + j*16 + fr;
      #pragma unroll
      for (int qi = 0; qi < 4; ++qi) {
        float val = acc[i][j][qi];
        size_t idx = (row0 + qi)*(size_t)ldc + col;
        if (EPI == 3) {
          float pv = __shfl_xor(val, 1, 64);
          int srow = (int)((row0 + qi) & 1023);
          int d = (int)(col & 63);
          float cs = costab[srow*64 + d];
          float sn = sintab[srow*64 + d];
          Cb[idx] = f2bf(val*cs + ((d & 1) ? pv : -pv)*sn);
        } else if (EPI == 4) {
          Cb[idx] = f2bf(val);
        } else {
          Cf[idx] = val;
        }
      }
    }
}

template<int EPI>
__global__ __launch_bounds__(256, 3) void gemm64(
    const unsigned short* __restrict__ A, const unsigned short* __restrict__ W,
    float* __restrict__ Cf, int K, int lda, int ldw, int ldc)
{
  gemm64_core<EPI>(A, W, Cf, nullptr, 0, K, lda, ldw, ldc, nullptr, nullptr);
}

// split-K: blockIdx.z = k-slice; writes partial C to P + z*(B*S*ldc)
__global__ __launch_bounds__(256, 3) void gemm64_ksplit(
    const unsigned short* __restrict__ A, const unsigned short* __restrict__ W,
    float* __restrict__ P, int Kslice, int lda, int ldw, int ldc)
{
  float* out = P + (size_t)blockIdx.z * (size_t)B_ * S_ * ldc;
  gemm64_core<0>(A, W, out, nullptr, blockIdx.z*Kslice, Kslice, lda, ldw, ldc,
                 nullptr, nullptr);
}

__global__ __launch_bounds__(256, 3) void gemm_qkv64(
    const unsigned short* __restrict__ A,
    const unsigned short* __restrict__ Wq, const unsigned short* __restrict__ Wk,
    const unsigned short* __restrict__ Wv,
    unsigned short* __restrict__ Cq, unsigned short* __restrict__ Ck,
    unsigned short* __restrict__ Cv,
    const float* __restrict__ costab, const float* __restrict__ sintab)
{
  if (blockIdx.z == 0)
    gemm64_core<3>(A, Wq, nullptr, Cq, 0, D_, D_, D_, D_, costab, sintab);
  else if (blockIdx.z == 1)
    gemm64_core<3>(A, Wk, nullptr, Ck, 0, D_, D_, D_, D_, costab, sintab);
  else
    gemm64_core<4>(A, Wv, nullptr, Cv, 0, D_, D_, D_, D_, nullptr, nullptr);
}

// ---------------- host launcher -----------------------------------------------
extern "C" void kernel_launch(void* const* d_in, const int* in_sizes, int n_in,
                              void* d_out, int out_size, void* d_ws, size_t ws_size,
                              hipStream_t stream)
{
  const int*   tokens    = (const int*)d_in[0];
  const int*   mood      = (const int*)d_in[1];
  const int*   raga      = (const int*)d_in[2];
  const int*   taal      = (const int*)d_in[3];
  const float* tempo     = (const float*)d_in[4];
  const float* duration  = (const float*)d_in[5];
  const int*   tcl       = (const int*)d_in[6];
  const float* tok_emb   = (const float*)d_in[7];
  const float* mood_emb  = (const float*)d_in[8];
  const float* raga_emb  = (const float*)d_in[9];
  const float* taal_emb  = (const float*)d_in[10];
  const float* tempo_w   = (const float*)d_in[11];
  const float* tempo_b   = (const float*)d_in[12];
  const float* dur_w     = (const float*)d_in[13];
  const float* dur_b     = (const float*)d_in[14];
  const float* proj_w    = (const float*)d_in[15];
  const float* proj_b    = (const float*)d_in[16];
  const float* ln_g      = (const float*)d_in[17];
  const float* ln_b      = (const float*)d_in[18];
  const float* cycle_emb = (const float*)d_in[19];
  const float* strength_e= (const float*)d_in[20];
  const float* l_anorm   = (const float*)d_in[21];
  const float* l_fnorm   = (const float*)d_in[22];
  const float* l_q       = (const float*)d_in[23];
  const float* l_k       = (const float*)d_in[24];
  const float* l_v       = (const float*)d_in[25];
  const float* l_o       = (const float*)d_in[26];
  const float* l_w1      = (const float*)d_in[27];
  const float* l_w2      = (const float*)d_in[28];
  const float* l_w3      = (const float*)d_in[29];
  const float* final_norm= (const float*)d_in[30];
  const float* head_w    = (const float*)d_in[31];

  size_t off = 0;
  char* wsb = (char*)d_ws;
  auto alloc = [&](size_t bytes) -> char* {
    char* p = wsb + off;
    off += (bytes + 255) & ~(size_t)255;
    return p;
  };
  float*          condb  = (float*)alloc((size_t)B_*D_*4);
  float*          costab = (float*)alloc((size_t)S_*HD_*4);
  float*          sintab = (float*)alloc((size_t)S_*HD_*4);
  float*          x      = (float*)alloc((size_t)B_*S_*D_*4);
  unsigned short* hbuf   = (unsigned short*)alloc((size_t)B_*S_*D_*2);
  unsigned short* qb     = (unsigned short*)alloc((size_t)B_*S_*D_*2);
  unsigned short* kb     = (unsigned short*)alloc((size_t)B_*S_*D_*2);
  unsigned short* vb     = (unsigned short*)alloc((size_t)B_*S_*D_*2);
  unsigned short* yb     = (unsigned short*)alloc((size_t)B_*S_*D_*2);
  unsigned short* tb     = (unsigned short*)alloc((size_t)B_*S_*FF_*2);
  float*          pbuf   = (float*)alloc((size_t)4*B_*S_*D_*4);   // split-K partials

  const size_t N_QKVO = (size_t)L_*D_*D_;
  const size_t N_FF   = (size_t)L_*FF_*D_;
  const size_t N_HEAD = (size_t)V_*D_;
  unsigned short* wbf = (unsigned short*)alloc((4*N_QKVO + 3*N_FF + N_HEAD)*2);
  unsigned short* bq = wbf;
  unsigned short* bk = wbf + N_QKVO;
  unsigned short* bv = wbf + 2*N_QKVO;
  unsigned short* bo = wbf + 3*N_QKVO;
  unsigned short* b1 = wbf + 4*N_QKVO;
  unsigned short* b2 = wbf + 4*N_QKVO + N_FF;
  unsigned short* b3 = wbf + 4*N_QKVO + 2*N_FF;
  unsigned short* bh = wbf + 4*N_QKVO + 3*N_FF;

  rope_table_kernel<<<(S_*HD_)/256, 256, 0, stream>>>(costab, sintab);
  cond_kernel<<<B_, 256, 0, stream>>>(mood, raga, taal, tempo, duration,
      mood_emb, raga_emb, taal_emb, tempo_w, tempo_b, dur_w, dur_b,
      proj_w, proj_b, ln_g, ln_b, condb);
  embed_kernel<<<B_*S_, 256, 0, stream>>>(tokens, tok_emb, condb, cycle_emb,
      strength_e, tcl, x);

  cvt_kernel<<<(int)(N_QKVO/8/256), 256, 0, stream>>>(l_q,  bq, (int)(N_QKVO/8));
  cvt_kernel<<<(int)(N_QKVO/8/256), 256, 0, stream>>>(l_k,  bk, (int)(N_QKVO/8));
  cvt_kernel<<<(int)(N_QKVO/8/256), 256, 0, stream>>>(l_v,  bv, (int)(N_QKVO/8));
  cvt_kernel<<<(int)(N_QKVO/8/256), 256, 0, stream>>>(l_o,  bo, (int)(N_QKVO/8));
  cvt_kernel<<<(int)(N_FF/8/256),   256, 0, stream>>>(l_w1, b1, (int)(N_FF/8));
  cvt_kernel<<<(int)(N_FF/8/256),   256, 0, stream>>>(l_w2, b2, (int)(N_FF/8));
  cvt_kernel<<<(int)(N_FF/8/256),   256, 0, stream>>>(l_w3, b3, (int)(N_FF/8));
  cvt_kernel<<<(int)(N_HEAD/8/256), 256, 0, stream>>>(head_w, bh, (int)(N_HEAD/8));

  const int rows = B_*S_;   // 2048
  rmsnorm_kernel<<<rows, 256, 0, stream>>>(x, l_anorm, hbuf);
  for (int l = 0; l < L_; ++l) {
    size_t dd = (size_t)l*D_*D_;
    size_t fd = (size_t)l*FF_*D_;
    // QKV (+rope fused)
    gemm_qkv64<<<dim3(rows/128, D_/64, 3), 256, 0, stream>>>(
        hbuf, bq + dd, bk + dd, bv + dd, qb, kb, vb, costab, sintab);
    attn_mfma<<<dim3(S_/64, H_, B_), 256, 0, stream>>>(qb, kb, vb, yb);
    // O-proj: split-K=2 -> partials; fused resid+rmsnorm(fnorm)
    gemm64_ksplit<<<dim3(rows/128, D_/64, 2), 256, 0, stream>>>(
        yb, bo + dd, pbuf, 512, D_, D_, D_);
    resid_rmsnorm_kernel<<<rows, 256, 0, stream>>>(
        x, pbuf, 2, l_fnorm + (size_t)l*D_, hbuf);
    // FFN
    gemm_w13<<<dim3(rows/128, FF_/128), 256, 0, stream>>>(
        hbuf, b1 + fd, b3 + fd, tb, D_, D_, D_);
    // W2: split-K=4 -> partials; fused resid+rmsnorm(next anorm / final)
    gemm64_ksplit<<<dim3(rows/128, D_/64, 4), 256, 0, stream>>>(
        tb, b2 + fd, pbuf, 1024, FF_, FF_, D_);
    const float* nextw = (l+1 < L_) ? (l_anorm + (size_t)(l+1)*D_) : final_norm;
    resid_rmsnorm_kernel<<<rows, 256, 0, stream>>>(x, pbuf, 4, nextw, hbuf);
  }
  gemm64<0><<<dim3(rows/128, V_/64), 256, 0, stream>>>(
      hbuf, bh, (float*)d_out, D_, D_, D_, V_);
}

// Round 7
// 1583.377 us; speedup vs baseline: 3.3283x; 1.1252x over previous
//
#include <hip/hip_runtime.h>
#include <math.h>

#define D_ 1024
#define H_ 16
#define HD_ 64
#define L_ 8
#define V_ 2048
#define FF_ 4096
#define WIN_ 256
#define B_ 2
#define S_ 1024
#define MAXCYC_ 16

typedef __attribute__((ext_vector_type(4))) float f32x4;
typedef __attribute__((ext_vector_type(8))) short s16x8;

__device__ __forceinline__ unsigned short f2bf(float f) {
  union { float f; unsigned int u; } v; v.f = f;
  unsigned int r = v.u + 0x7FFFu + ((v.u >> 16) & 1u);
  return (unsigned short)(r >> 16);
}

__device__ __forceinline__ float wave_sum(float v) {
  #pragma unroll
  for (int m = 1; m < 64; m <<= 1) v += __shfl_xor(v, m, 64);
  return v;
}

// async global->LDS, 16B per lane. dst wave-uniform base; HW writes dst+lane*16.
__device__ __forceinline__ void gload16(const unsigned short* g, unsigned short* lds) {
  __builtin_amdgcn_global_load_lds(
      (const __attribute__((address_space(1))) void*)g,
      (__attribute__((address_space(3))) void*)lds,
      16, 0, 0);
}

// ---------------- f32 -> bf16 convert (weights) ------------------------------
__global__ __launch_bounds__(256) void cvt_kernel(
    const float* __restrict__ src, unsigned short* __restrict__ dst, int n8)
{
  int i = blockIdx.x*256 + threadIdx.x;
  if (i >= n8) return;
  const float4* s = (const float4*)src + (size_t)i*2;
  float4 a = s[0], b = s[1];
  ushort4 lo, hi;
  lo.x = f2bf(a.x); lo.y = f2bf(a.y); lo.z = f2bf(a.z); lo.w = f2bf(a.w);
  hi.x = f2bf(b.x); hi.y = f2bf(b.y); hi.z = f2bf(b.z); hi.w = f2bf(b.w);
  *(ushort4*)(dst + (size_t)i*8)     = lo;
  *(ushort4*)(dst + (size_t)i*8 + 4) = hi;
}

// ---------------- conditioning ----------------------------------------------
__global__ __launch_bounds__(256) void cond_kernel(
    const int* mood, const int* raga, const int* taal,
    const float* tempo, const float* duration,
    const float* mood_emb, const float* raga_emb, const float* taal_emb,
    const float* tempo_w, const float* tempo_b, const float* dur_w, const float* dur_b,
    const float* proj_w, const float* proj_b, const float* ln_g, const float* ln_b,
    float* cond)
{
  int b = blockIdx.x;
  int t = threadIdx.x;
  __shared__ float feat[192];
  __shared__ float red[4];
  if (t < 64)        feat[t] = mood_emb[mood[b]*64 + t];
  else if (t < 128)  feat[t] = raga_emb[raga[b]*64 + (t-64)];
  else if (t < 160)  feat[t] = taal_emb[taal[b]*32 + (t-128)];
  else if (t < 176)  feat[t] = tempo[b]*tempo_w[t-160] + tempo_b[t-160];
  else if (t < 192)  feat[t] = duration[b]*dur_w[t-176] + dur_b[t-176];
  __syncthreads();
  float g[4];
  #pragma unroll
  for (int r = 0; r < 4; ++r) {
    int j = t + 256*r;
    const float* w = proj_w + (size_t)j*192;
    float acc = proj_b[j];
    for (int f = 0; f < 192; ++f) acc += feat[f]*w[f];
    g[r] = 0.5f * acc * (1.0f + erff(acc * 0.7071067811865475f));
  }
  int lane = t & 63, wv = t >> 6;
  float s1 = g[0]+g[1]+g[2]+g[3];
  s1 = wave_sum(s1);
  if (lane == 0) red[wv] = s1;
  __syncthreads();
  float mu = (red[0]+red[1]+red[2]+red[3]) * (1.0f/1024.0f);
  __syncthreads();
  float vs = 0.f;
  #pragma unroll
  for (int r = 0; r < 4; ++r) { float d = g[r]-mu; vs += d*d; }
  vs = wave_sum(vs);
  if (lane == 0) red[wv] = vs;
  __syncthreads();
  float var = (red[0]+red[1]+red[2]+red[3]) * (1.0f/1024.0f);
  float is = rsqrtf(var + 1e-5f);
  #pragma unroll
  for (int r = 0; r < 4; ++r) {
    int j = t + 256*r;
    cond[(size_t)b*D_ + j] = (g[r]-mu)*is*ln_g[j] + ln_b[j];
  }
}

// ---------------- embedding sum ----------------------------------------------
__global__ __launch_bounds__(256) void embed_kernel(
    const int* tokens, const float* tok_emb, const float* cond,
    const float* cycle_emb, const float* strength_emb, const int* tcl_p, float* x)
{
  int row = blockIdx.x;
  int b = row >> 10, s = row & 1023;
  int tcl = tcl_p[0];
  int cyc = tcl < MAXCYC_ ? tcl : MAXCYC_;
  int pr  = s % cyc;
  int str = (s % tcl == 0) ? 0 : 3;
  int tok = tokens[row];
  int d = threadIdx.x * 4;
  float4 a = *(const float4*)&tok_emb[(size_t)tok*D_ + d];
  float4 c = *(const float4*)&cond[(size_t)b*D_ + d];
  float4 p = *(const float4*)&cycle_emb[(size_t)pr*D_ + d];
  float4 e = *(const float4*)&strength_emb[(size_t)str*D_ + d];
  float4 o; o.x=a.x+c.x+p.x+e.x; o.y=a.y+c.y+p.y+e.y; o.z=a.z+c.z+p.z+e.z; o.w=a.w+c.w+p.w+e.w;
  *(float4*)&x[(size_t)row*D_ + d] = o;
}

// ---------------- rmsnorm -> bf16 --------------------------------------------
__global__ __launch_bounds__(256) void rmsnorm_kernel(
    const float* x, const float* w, unsigned short* out)
{
  int row = blockIdx.x;
  int t = threadIdx.x;
  __shared__ float red[4];
  const float* xr = x + (size_t)row*D_;
  float4 v = *(const float4*)&xr[t*4];
  float ss = v.x*v.x + v.y*v.y + v.z*v.z + v.w*v.w;
  ss = wave_sum(ss);
  int lane = t & 63, wv = t >> 6;
  if (lane == 0) red[wv] = ss;
  __syncthreads();
  float total = red[0]+red[1]+red[2]+red[3];
  float scale = rsqrtf(total * (1.0f/1024.0f) + 1e-5f);
  float4 wv4 = *(const float4*)&w[t*4];
  ushort4 o;
  o.x = f2bf(wv4.x * v.x * scale);
  o.y = f2bf(wv4.y * v.y * scale);
  o.z = f2bf(wv4.z * v.z * scale);
  o.w = f2bf(wv4.w * v.w * scale);
  *(ushort4*)&out[(size_t)row*D_ + t*4] = o;
}

// -------- fused: x += sum(partials); rmsnorm(x) -> bf16 -----------------------
__global__ __launch_bounds__(256) void resid_rmsnorm_kernel(
    float* __restrict__ x, const float* __restrict__ part, int nparts,
    const float* __restrict__ w, unsigned short* __restrict__ out)
{
  int row = blockIdx.x;
  int t = threadIdx.x;
  __shared__ float red[4];
  size_t base = (size_t)row*D_ + t*4;
  const size_t pstride = (size_t)B_*S_*D_;
  float4 v = *(const float4*)&x[base];
  for (int p = 0; p < nparts; ++p) {
    float4 a = *(const float4*)&part[p*pstride + base];
    v.x += a.x; v.y += a.y; v.z += a.z; v.w += a.w;
  }
  *(float4*)&x[base] = v;
  float ss = v.x*v.x + v.y*v.y + v.z*v.z + v.w*v.w;
  ss = wave_sum(ss);
  int lane = t & 63, wv = t >> 6;
  if (lane == 0) red[wv] = ss;
  __syncthreads();
  float total = red[0]+red[1]+red[2]+red[3];
  float scale = rsqrtf(total * (1.0f/1024.0f) + 1e-5f);
  float4 wv4 = *(const float4*)&w[t*4];
  ushort4 o;
  o.x = f2bf(wv4.x * v.x * scale);
  o.y = f2bf(wv4.y * v.y * scale);
  o.z = f2bf(wv4.z * v.z * scale);
  o.w = f2bf(wv4.w * v.w * scale);
  *(ushort4*)&out[(size_t)row*D_ + t*4] = o;
}

// ---------------- rope tables -------------------------------------------------
__global__ __launch_bounds__(256) void rope_table_kernel(float* costab, float* sintab)
{
  int i = blockIdx.x*256 + threadIdx.x;
  int s = i >> 6, d = i & 63;
  float inv = powf(10000.0f, -(float)(d & 31) * (1.0f/32.0f));
  float ang = (float)s * inv;
  float sn, cs;
  sincosf(ang, &sn, &cs);
  costab[i] = cs; sintab[i] = sn;
}

// =============== MFMA sliding-window flash attention ==========================
__global__ __launch_bounds__(256) void attn_mfma(
    const unsigned short* __restrict__ q, const unsigned short* __restrict__ k,
    const unsigned short* __restrict__ v, unsigned short* __restrict__ y)
{
  __shared__ unsigned short Ks[64*64];     // [key][d], 128B rows, chunk-swizzled
  __shared__ unsigned short VsT[64*72];    // [d][key], ld=72
  __shared__ unsigned short Ps[4*16*72];   // per-wave P / output tile

  int qb0 = blockIdx.x * 64;
  int h = blockIdx.y, b = blockIdx.z;
  int t = threadIdx.x, lane = t & 63, wv = t >> 6;
  int c = lane & 15, q4 = lane >> 4;
  unsigned short* Pw = &Ps[wv*16*72];

  s16x8 aq[2];
  {
    const unsigned short* qp =
        q + ((size_t)(b*S_ + qb0 + wv*16 + c)*D_ + h*HD_ + q4*8);
    aq[0] = *(const s16x8*)qp;
    aq[1] = *(const s16x8*)(qp + 32);
  }

  f32x4 o[4];
  #pragma unroll
  for (int j = 0; j < 4; ++j) o[j] = (f32x4){0.f,0.f,0.f,0.f};
  float m[4] = {-1e30f,-1e30f,-1e30f,-1e30f};
  float l[4] = {0.f,0.f,0.f,0.f};

  int skey = t >> 2;
  int scol = (t & 3) * 16;
  int kt0 = qb0 - 256; if (kt0 < 0) kt0 = 0;

  for (int kt = kt0; kt <= qb0; kt += 64) {
    __syncthreads();
    {
      const unsigned short* kp = k + ((size_t)(b*S_ + kt + skey)*D_ + h*HD_ + scol);
      s16x8 k0 = *(const s16x8*)kp;
      s16x8 k1 = *(const s16x8*)(kp + 8);
      int ch0 = scol >> 3;
      *(s16x8*)((char*)Ks + skey*128 + ((ch0 ^ (skey & 7)) << 4)) = k0;
      *(s16x8*)((char*)Ks + skey*128 + (((ch0+1) ^ (skey & 7)) << 4)) = k1;
      const unsigned short* vp = v + ((size_t)(b*S_ + kt + skey)*D_ + h*HD_ + scol);
      s16x8 v0 = *(const s16x8*)vp;
      s16x8 v1 = *(const s16x8*)(vp + 8);
      #pragma unroll
      for (int i = 0; i < 8; ++i) {
        VsT[(scol + i)*72 + skey]     = (unsigned short)v0[i];
        VsT[(scol + 8 + i)*72 + skey] = (unsigned short)v1[i];
      }
    }
    __syncthreads();

    f32x4 sa[4];
    #pragma unroll
    for (int j = 0; j < 4; ++j) sa[j] = (f32x4){0.f,0.f,0.f,0.f};
    __builtin_amdgcn_s_setprio(1);
    #pragma unroll
    for (int ks = 0; ks < 2; ++ks)
      #pragma unroll
      for (int j = 0; j < 4; ++j) {
        int key = j*16 + c;
        s16x8 bk = *(const s16x8*)((const char*)Ks + key*128 +
                                   (((q4 + ks*4) ^ (key & 7)) << 4));
        sa[j] = __builtin_amdgcn_mfma_f32_16x16x32_bf16(aq[ks], bk, sa[j], 0, 0, 0);
      }
    __builtin_amdgcn_s_setprio(0);

    float sv[4][4];
    #pragma unroll
    for (int j = 0; j < 4; ++j) {
      int kg = kt + j*16 + c;
      #pragma unroll
      for (int reg = 0; reg < 4; ++reg) {
        int qg = qb0 + wv*16 + q4*4 + reg;
        bool ok = (qg >= kg) && (qg - kg < WIN_);
        sv[j][reg] = ok ? sa[j][reg]*0.125f : -3e38f;
      }
    }
    #pragma unroll
    for (int reg = 0; reg < 4; ++reg) {
      float mx = fmaxf(fmaxf(sv[0][reg], sv[1][reg]), fmaxf(sv[2][reg], sv[3][reg]));
      #pragma unroll
      for (int msk = 1; msk < 16; msk <<= 1)
        mx = fmaxf(mx, __shfl_xor(mx, msk, 64));
      float nm = fmaxf(m[reg], mx);
      float f = __expf(m[reg] - nm);
      m[reg] = nm;
      l[reg] *= f;
      o[0][reg] *= f; o[1][reg] *= f; o[2][reg] *= f; o[3][reg] *= f;
      float ps = 0.f;
      #pragma unroll
      for (int j = 0; j < 4; ++j) {
        float p = __expf(sv[j][reg] - nm);
        ps += p;
        Pw[(q4*4 + reg)*72 + j*16 + c] = f2bf(p);
      }
      l[reg] += ps;
    }

    __builtin_amdgcn_s_setprio(1);
    #pragma unroll
    for (int ks = 0; ks < 2; ++ks) {
      s16x8 pa = *(const s16x8*)((const char*)Pw + c*144 + (q4 + ks*4)*16);
      #pragma unroll
      for (int j = 0; j < 4; ++j) {
        s16x8 bv = *(const s16x8*)((const char*)VsT + (j*16 + c)*144 + (q4 + ks*4)*16);
        o[j] = __builtin_amdgcn_mfma_f32_16x16x32_bf16(pa, bv, o[j], 0, 0, 0);
      }
    }
    __builtin_amdgcn_s_setprio(0);
  }

  float inv[4];
  #pragma unroll
  for (int reg = 0; reg < 4; ++reg) {
    float ll = l[reg];
    #pragma unroll
    for (int msk = 1; msk < 16; msk <<= 1) ll += __shfl_xor(ll, msk, 64);
    inv[reg] = 1.0f / ll;
  }
  #pragma unroll
  for (int j = 0; j < 4; ++j)
    #pragma unroll
    for (int reg = 0; reg < 4; ++reg)
      Pw[(q4*4 + reg)*72 + j*16 + c] = f2bf(o[j][reg] * inv[reg]);
  int lr = lane >> 2, cc = (lane & 3)*16;
  s16x8 y0 = *(const s16x8*)((const char*)Pw + lr*144 + cc*2);
  s16x8 y1 = *(const s16x8*)((const char*)Pw + lr*144 + cc*2 + 16);
  unsigned short* yp = y + ((size_t)(b*S_ + qb0 + wv*16 + lr)*D_ + h*HD_ + cc);
  *(s16x8*)yp = y0;
  *(s16x8*)(yp + 8) = y1;
}

// ===== fused W1/W3 GEMM: 128x128, BK=32, depth-2 pipeline, 2 barriers/step ====
// Race-free: barrier B after MFMA guarantees all waves' ds_reads of buf
// (t-1)%3 retired before any wave issues stage(t+2) into that buffer.
__global__ __launch_bounds__(256, 2) void gemm_w13(
    const unsigned short* __restrict__ A,
    const unsigned short* __restrict__ W1, const unsigned short* __restrict__ W3,
    unsigned short* __restrict__ T, int K, int lda, int ldw)
{
  __shared__ unsigned short sA[3][128*32];
  __shared__ unsigned short sW1[3][128*32];
  __shared__ unsigned short sW3[3][128*32];
  int tid = threadIdx.x, lane = tid & 63, wave = tid >> 6;
  int wr = (wave >> 1)*64, wc = (wave & 1)*64;
  size_t bm = (size_t)blockIdx.x*128, bn = (size_t)blockIdx.y*128;
  int fr = lane & 15, q4 = lane >> 4, fq = q4*4;
  int lrow = lane >> 2;                                  // 0..15
  int gcol = ((lane & 3) ^ ((lrow >> 1) & 3)) * 8;       // pre-swizzled chunk

  f32x4 a1[4][4], a3[4][4];
  #pragma unroll
  for (int i = 0; i < 4; ++i)
    #pragma unroll
    for (int j = 0; j < 4; ++j) {
      a1[i][j] = (f32x4){0.f,0.f,0.f,0.f};
      a3[i][j] = (f32x4){0.f,0.f,0.f,0.f};
    }

  auto stage = [&](int buf, int kt) {   // 6 vmem ops per lane
    #pragma unroll
    for (int p = 0; p < 2; ++p) {
      int seg = wave*2 + p;
      size_t row = (size_t)(seg*16 + lrow);
      gload16(A  + (bm + row)*(size_t)lda + kt + gcol, &sA[buf][seg*512]);
      gload16(W1 + (bn + row)*(size_t)ldw + kt + gcol, &sW1[buf][seg*512]);
      gload16(W3 + (bn + row)*(size_t)ldw + kt + gcol, &sW3[buf][seg*512]);
    }
  };

  int nt = K >> 5;
  stage(0, 0);
  stage(1, 32);
  for (int t = 0; t < nt; ++t) {
    int cur = t % 3;
    if (t + 2 < nt) {
      stage((t+2)%3, (t+2)*32);
      asm volatile("s_waitcnt vmcnt(12)" ::: "memory");
    } else if (t + 1 < nt) {
      asm volatile("s_waitcnt vmcnt(6)" ::: "memory");
    } else {
      asm volatile("s_waitcnt vmcnt(0)" ::: "memory");
    }
    __builtin_amdgcn_sched_barrier(0);
    __builtin_amdgcn_s_barrier();          // A: buf[cur] fully staged
    __builtin_amdgcn_sched_barrier(0);
    s16x8 af[4], b1[4], b3[4];
    #pragma unroll
    for (int i = 0; i < 4; ++i) {
      int ra = wr + i*16 + fr, rb = wc + i*16 + fr;
      af[i] = *(const s16x8*)((const char*)&sA[cur][0]  + ra*64 + ((q4 ^ ((ra>>1)&3)) << 4));
      b1[i] = *(const s16x8*)((const char*)&sW1[cur][0] + rb*64 + ((q4 ^ ((rb>>1)&3)) << 4));
      b3[i] = *(const s16x8*)((const char*)&sW3[cur][0] + rb*64 + ((q4 ^ ((rb>>1)&3)) << 4));
    }
    __builtin_amdgcn_s_setprio(1);
    #pragma unroll
    for (int i = 0; i < 4; ++i)
      #pragma unroll
      for (int j = 0; j < 4; ++j) {
        a1[i][j] = __builtin_amdgcn_mfma_f32_16x16x32_bf16(af[i], b1[j], a1[i][j], 0, 0, 0);
        a3[i][j] = __builtin_amdgcn_mfma_f32_16x16x32_bf16(af[i], b3[j], a3[i][j], 0, 0, 0);
      }
    __builtin_amdgcn_s_setprio(0);
    __builtin_amdgcn_sched_barrier(0);
    __builtin_amdgcn_s_barrier();          // B: all reads of buf[cur] retired
    __builtin_amdgcn_sched_barrier(0);
  }

  #pragma unroll
  for (int i = 0; i < 4; ++i)
    #pragma unroll
    for (int j = 0; j < 4; ++j) {
      size_t row0 = bm + wr + i*16 + fq;
      size_t col  = bn + wc + j*16 + fr;
      #pragma unroll
      for (int qi = 0; qi < 4; ++qi) {
        float u = a1[i][j][qi];
        float g = a3[i][j][qi];
        float su = u / (1.0f + __expf(-u));
        T[(row0 + qi)*(size_t)FF_ + col] = f2bf(su * g);
      }
    }
}

// ===== generic GEMM: 128x64, BK=32, depth-2 pipeline, 2 barriers/step =========
// EPI: 0 = store f32, 3 = rope->bf16, 4 = bf16
template<int EPI>
__device__ __forceinline__ void gemm64_core(
    const unsigned short* __restrict__ A, const unsigned short* __restrict__ W,
    float* __restrict__ Cf, unsigned short* __restrict__ Cb,
    int kbase, int Kslice, int lda, int ldw, int ldc,
    const float* __restrict__ costab, const float* __restrict__ sintab)
{
  __shared__ unsigned short sA[3][128*32];
  __shared__ unsigned short sW[3][64*32];
  int tid = threadIdx.x, lane = tid & 63, wave = tid >> 6;
  int wr = (wave >> 1)*64, wc = (wave & 1)*32;
  size_t bm = (size_t)blockIdx.x*128, bn = (size_t)blockIdx.y*64;
  int fr = lane & 15, q4 = lane >> 4, fq = q4*4;
  int lrow = lane >> 2;                                  // 0..15
  int gcol = ((lane & 3) ^ ((lrow >> 1) & 3)) * 8;       // pre-swizzled chunk

  f32x4 acc[4][2];
  #pragma unroll
  for (int i = 0; i < 4; ++i) {
    acc[i][0] = (f32x4){0.f,0.f,0.f,0.f};
    acc[i][1] = (f32x4){0.f,0.f,0.f,0.f};
  }

  auto stage = [&](int buf, int kt) {   // 3 vmem ops per lane
    #pragma unroll
    for (int p = 0; p < 2; ++p) {
      int seg = wave*2 + p;
      gload16(A + (bm + seg*16 + lrow)*(size_t)lda + kt + gcol, &sA[buf][seg*512]);
    }
    gload16(W + (bn + wave*16 + lrow)*(size_t)ldw + kt + gcol, &sW[buf][wave*512]);
  };

  int nt = Kslice >> 5;
  stage(0, kbase);
  stage(1, kbase + 32);
  for (int t = 0; t < nt; ++t) {
    int cur = t % 3;
    if (t + 2 < nt) {
      stage((t+2)%3, kbase + (t+2)*32);
      asm volatile("s_waitcnt vmcnt(6)" ::: "memory");
    } else if (t + 1 < nt) {
      asm volatile("s_waitcnt vmcnt(3)" ::: "memory");
    } else {
      asm volatile("s_waitcnt vmcnt(0)" ::: "memory");
    }
    __builtin_amdgcn_sched_barrier(0);
    __builtin_amdgcn_s_barrier();          // A: buf[cur] fully staged
    __builtin_amdgcn_sched_barrier(0);
    s16x8 af[4], bw[2];
    #pragma unroll
    for (int i = 0; i < 4; ++i) {
      int r = wr + i*16 + fr;
      af[i] = *(const s16x8*)((const char*)&sA[cur][0] + r*64 + ((q4 ^ ((r>>1)&3)) << 4));
    }
    #pragma unroll
    for (int j = 0; j < 2; ++j) {
      int r = wc + j*16 + fr;
      bw[j] = *(const s16x8*)((const char*)&sW[cur][0] + r*64 + ((q4 ^ ((r>>1)&3)) << 4));
    }
    __builtin_amdgcn_s_setprio(1);
    #pragma unroll
    for (int i = 0; i < 4; ++i)
      #pragma unroll
      for (int j = 0; j < 2; ++j)
        acc[i][j] = __builtin_amdgcn_mfma_f32_16x16x32_bf16(af[i], bw[j], acc[i][j], 0, 0, 0);
    __builtin_amdgcn_s_setprio(0);
    __builtin_amdgcn_sched_barrier(0);
    __builtin_amdgcn_s_barrier();          // B: all reads of buf[cur] retired
    __builtin_amdgcn_sched_barrier(0);
  }

  #pragma unroll
  for (int i = 0; i < 4; ++i)
    #pragma unroll
    for (int j = 0; j < 2; ++j) {
      size_t row0 = bm + wr + i*16 + fq;
      size_t col  = bn + wc + j*16 + fr;
      #pragma unroll
      for (int qi = 0; qi < 4; ++qi) {
        float val = acc[i][j][qi];
        size_t idx = (row0 + qi)*(size_t)ldc + col;
        if (EPI == 3) {
          float pv = __shfl_xor(val, 1, 64);
          int srow = (int)((row0 + qi) & 1023);
          int d = (int)(col & 63);
          float cs = costab[srow*64 + d];
          float sn = sintab[srow*64 + d];
          Cb[idx] = f2bf(val*cs + ((d & 1) ? pv : -pv)*sn);
        } else if (EPI == 4) {
          Cb[idx] = f2bf(val);
        } else {
          Cf[idx] = val;
        }
      }
    }
}

template<int EPI>
__global__ __launch_bounds__(256, 3) void gemm64(
    const unsigned short* __restrict__ A, const unsigned short* __restrict__ W,
    float* __restrict__ Cf, int K, int lda, int ldw, int ldc)
{
  gemm64_core<EPI>(A, W, Cf, nullptr, 0, K, lda, ldw, ldc, nullptr, nullptr);
}

// split-K: blockIdx.z = k-slice; writes partial C to P + z*(B*S*ldc)
__global__ __launch_bounds__(256, 3) void gemm64_ksplit(
    const unsigned short* __restrict__ A, const unsigned short* __restrict__ W,
    float* __restrict__ P, int Kslice, int lda, int ldw, int ldc)
{
  float* out = P + (size_t)blockIdx.z * (size_t)B_ * S_ * ldc;
  gemm64_core<0>(A, W, out, nullptr, blockIdx.z*Kslice, Kslice, lda, ldw, ldc,
                 nullptr, nullptr);
}

__global__ __launch_bounds__(256, 3) void gemm_qkv64(
    const unsigned short* __restrict__ A,
    const unsigned short* __restrict__ Wq, const unsigned short* __restrict__ Wk,
    const unsigned short* __restrict__ Wv,
    unsigned short* __restrict__ Cq, unsigned short* __restrict__ Ck,
    unsigned short* __restrict__ Cv,
    const float* __restrict__ costab, const float* __restrict__ sintab)
{
  if (blockIdx.z == 0)
    gemm64_core<3>(A, Wq, nullptr, Cq, 0, D_, D_, D_, D_, costab, sintab);
  else if (blockIdx.z == 1)
    gemm64_core<3>(A, Wk, nullptr, Ck, 0, D_, D_, D_, D_, costab, sintab);
  else
    gemm64_core<4>(A, Wv, nullptr, Cv, 0, D_, D_, D_, D_, nullptr, nullptr);
}

// ---------------- host launcher -----------------------------------------------
extern "C" void kernel_launch(void* const* d_in, const int* in_sizes, int n_in,
                              void* d_out, int out_size, void* d_ws, size_t ws_size,
                              hipStream_t stream)
{
  const int*   tokens    = (const int*)d_in[0];
  const int*   mood      = (const int*)d_in[1];
  const int*   raga      = (const int*)d_in[2];
  const int*   taal      = (const int*)d_in[3];
  const float* tempo     = (const float*)d_in[4];
  const float* duration  = (const float*)d_in[5];
  const int*   tcl       = (const int*)d_in[6];
  const float* tok_emb   = (const float*)d_in[7];
  const float* mood_emb  = (const float*)d_in[8];
  const float* raga_emb  = (const float*)d_in[9];
  const float* taal_emb  = (const float*)d_in[10];
  const float* tempo_w   = (const float*)d_in[11];
  const float* tempo_b   = (const float*)d_in[12];
  const float* dur_w     = (const float*)d_in[13];
  const float* dur_b     = (const float*)d_in[14];
  const float* proj_w    = (const float*)d_in[15];
  const float* proj_b    = (const float*)d_in[16];
  const float* ln_g      = (const float*)d_in[17];
  const float* ln_b      = (const float*)d_in[18];
  const float* cycle_emb = (const float*)d_in[19];
  const float* strength_e= (const float*)d_in[20];
  const float* l_anorm   = (const float*)d_in[21];
  const float* l_fnorm   = (const float*)d_in[22];
  const float* l_q       = (const float*)d_in[23];
  const float* l_k       = (const float*)d_in[24];
  const float* l_v       = (const float*)d_in[25];
  const float* l_o       = (const float*)d_in[26];
  const float* l_w1      = (const float*)d_in[27];
  const float* l_w2      = (const float*)d_in[28];
  const float* l_w3      = (const float*)d_in[29];
  const float* final_norm= (const float*)d_in[30];
  const float* head_w    = (const float*)d_in[31];

  size_t off = 0;
  char* wsb = (char*)d_ws;
  auto alloc = [&](size_t bytes) -> char* {
    char* p = wsb + off;
    off += (bytes + 255) & ~(size_t)255;
    return p;
  };
  float*          condb  = (float*)alloc((size_t)B_*D_*4);
  float*          costab = (float*)alloc((size_t)S_*HD_*4);
  float*          sintab = (float*)alloc((size_t)S_*HD_*4);
  float*          x      = (float*)alloc((size_t)B_*S_*D_*4);
  unsigned short* hbuf   = (unsigned short*)alloc((size_t)B_*S_*D_*2);
  unsigned short* qb     = (unsigned short*)alloc((size_t)B_*S_*D_*2);
  unsigned short* kb     = (unsigned short*)alloc((size_t)B_*S_*D_*2);
  unsigned short* vb     = (unsigned short*)alloc((size_t)B_*S_*D_*2);
  unsigned short* yb     = (unsigned short*)alloc((size_t)B_*S_*D_*2);
  unsigned short* tb     = (unsigned short*)alloc((size_t)B_*S_*FF_*2);
  float*          pbuf   = (float*)alloc((size_t)4*B_*S_*D_*4);   // split-K partials

  const size_t N_QKVO = (size_t)L_*D_*D_;
  const size_t N_FF   = (size_t)L_*FF_*D_;
  const size_t N_HEAD = (size_t)V_*D_;
  unsigned short* wbf = (unsigned short*)alloc((4*N_QKVO + 3*N_FF + N_HEAD)*2);
  unsigned short* bq = wbf;
  unsigned short* bk = wbf + N_QKVO;
  unsigned short* bv = wbf + 2*N_QKVO;
  unsigned short* bo = wbf + 3*N_QKVO;
  unsigned short* b1 = wbf + 4*N_QKVO;
  unsigned short* b2 = wbf + 4*N_QKVO + N_FF;
  unsigned short* b3 = wbf + 4*N_QKVO + 2*N_FF;
  unsigned short* bh = wbf + 4*N_QKVO + 3*N_FF;

  rope_table_kernel<<<(S_*HD_)/256, 256, 0, stream>>>(costab, sintab);
  cond_kernel<<<B_, 256, 0, stream>>>(mood, raga, taal, tempo, duration,
      mood_emb, raga_emb, taal_emb, tempo_w, tempo_b, dur_w, dur_b,
      proj_w, proj_b, ln_g, ln_b, condb);
  embed_kernel<<<B_*S_, 256, 0, stream>>>(tokens, tok_emb, condb, cycle_emb,
      strength_e, tcl, x);

  cvt_kernel<<<(int)(N_QKVO/8/256), 256, 0, stream>>>(l_q,  bq, (int)(N_QKVO/8));
  cvt_kernel<<<(int)(N_QKVO/8/256), 256, 0, stream>>>(l_k,  bk, (int)(N_QKVO/8));
  cvt_kernel<<<(int)(N_QKVO/8/256), 256, 0, stream>>>(l_v,  bv, (int)(N_QKVO/8));
  cvt_kernel<<<(int)(N_QKVO/8/256), 256, 0, stream>>>(l_o,  bo, (int)(N_QKVO/8));
  cvt_kernel<<<(int)(N_FF/8/256),   256, 0, stream>>>(l_w1, b1, (int)(N_FF/8));
  cvt_kernel<<<(int)(N_FF/8/256),   256, 0, stream>>>(l_w2, b2, (int)(N_FF/8));
  cvt_kernel<<<(int)(N_FF/8/256),   256, 0, stream>>>(l_w3, b3, (int)(N_FF/8));
  cvt_kernel<<<(int)(N_HEAD/8/256), 256, 0, stream>>>(head_w, bh, (int)(N_HEAD/8));

  const int rows = B_*S_;   // 2048
  rmsnorm_kernel<<<rows, 256, 0, stream>>>(x, l_anorm, hbuf);
  for (int l = 0; l < L_; ++l) {
    size_t dd = (size_t)l*D_*D_;
    size_t fd = (size_t)l*FF_*D_;
    gemm_qkv64<<<dim3(rows/128, D_/64, 3), 256, 0, stream>>>(
        hbuf, bq + dd, bk + dd, bv + dd, qb, kb, vb, costab, sintab);
    attn_mfma<<<dim3(S_/64, H_, B_), 256, 0, stream>>>(qb, kb, vb, yb);
    gemm64_ksplit<<<dim3(rows/128, D_/64, 2), 256, 0, stream>>>(
        yb, bo + dd, pbuf, 512, D_, D_, D_);
    resid_rmsnorm_kernel<<<rows, 256, 0, stream>>>(
        x, pbuf, 2, l_fnorm + (size_t)l*D_, hbuf);
    gemm_w13<<<dim3(rows/128, FF_/128), 256, 0, stream>>>(
        hbuf, b1 + fd, b3 + fd, tb, D_, D_, D_);
    gemm64_ksplit<<<dim3(rows/128, D_/64, 4), 256, 0, stream>>>(
        tb, b2 + fd, pbuf, 1024, FF_, FF_, D_);
    const float* nextw = (l+1 < L_) ? (l_anorm + (size_t)(l+1)*D_) : final_norm;
    resid_rmsnorm_kernel<<<rows, 256, 0, stream>>>(x, pbuf, 4, nextw, hbuf);
  }
  gemm64<0><<<dim3(rows/128, V_/64), 256, 0, stream>>>(
      hbuf, bh, (float*)d_out, D_, D_, D_, V_);
}